// Round 12
// baseline (880.158 us; speedup 1.0000x reference)
//
#include <hip/hip_runtime.h>
#include <hip/hip_bf16.h>
#include <stdint.h>

// ---------------------------------------------------------------------------
// Network_60163901882451 — round 12: conv_tile v7 — zero-pad slot.
// x1/x2 stored [img][82][CI] with pixel slot 81 kept ZERO; invalid conv taps
// load slot 81 directly -> no cndmask/select on the A-path (r11 showed the
// select chain kept the compiler at ~1 A-load in flight, VGPR=80, 17% MFMA).
// x3 unpadded (encoder consumer). Rest identical to r11.
// ---------------------------------------------------------------------------

#define NIMG 8192
#define NPIX 81
#define PXP 82
#define FLAT 10368

typedef __hip_bfloat16 bf16;
typedef short bf16x8 __attribute__((ext_vector_type(8)));
typedef float f32x4 __attribute__((ext_vector_type(4)));

__device__ __forceinline__ float bflo(unsigned u) { return __uint_as_float(u << 16); }
__device__ __forceinline__ float bfhi(unsigned u) { return __uint_as_float(u & 0xffff0000u); }
__device__ __forceinline__ unsigned short f2bf(float f) {
    unsigned u = __float_as_uint(f);
    return (unsigned short)((u + 0x7fff + ((u >> 16) & 1)) >> 16);
}

__global__ void fill_sentinel(float* __restrict__ out, int n) {
    int i = blockIdx.x * 256 + threadIdx.x;
    if (i < n) out[i] = 1.0e9f;   // ws_size-too-small signature
}

// ---------------- weight preps ---------------------------------------------
__global__ void prep_w(const float* __restrict__ c1w, const float* __restrict__ c2w,
                       const float* __restrict__ c3w,
                       float* __restrict__ w1t, bf16* __restrict__ w2m,
                       bf16* __restrict__ w3m) {
    int i0 = blockIdx.x * blockDim.x + threadIdx.x;
    int stride = gridDim.x * blockDim.x;
    for (int i = i0; i < 27 * 32; i += stride) w1t[i] = c1w[(i & 31) * 27 + (i >> 5)];
    for (int i = i0; i < 64 * 288; i += stride) {
        int oc = i / 288, r = i - oc * 288, t = r >> 5, ci = r & 31;
        w2m[i] = __float2bfloat16(c2w[oc * 288 + ci * 9 + t]);
    }
    for (int i = i0; i < 128 * 576; i += stride) {
        int oc = i / 576, r = i - oc * 576, t = r >> 6, ci = r & 63;
        w3m[i] = __float2bfloat16(c3w[oc * 576 + ci * 9 + t]);
    }
}

// ewb[e][px*128+ci] = encw[e][ci*81+px]
__global__ void prep_enc(const float* __restrict__ encw, bf16* __restrict__ ewb) {
    int i0 = blockIdx.x * blockDim.x + threadIdx.x;
    int stride = gridDim.x * blockDim.x;
    for (int i = i0; i < 128 * FLAT; i += stride) {
        int e = i / FLAT, r = i - e * FLAT;
        int px = r >> 7, ci = r & 127;
        ewb[i] = __float2bfloat16(encw[(size_t)e * FLAT + ci * 81 + px]);
    }
}

// ---------------- conv1 (direct fp32; fused stats; padded out) -------------
__device__ __forceinline__ void load_row(const float* __restrict__ p, float* r) {
    float4 a = *(const float4*)p;
    float4 b = *(const float4*)(p + 4);
    float4 c = *(const float4*)(p + 8);
    r[0]=a.x; r[1]=a.y; r[2]=a.z;  r[3]=a.w;
    r[4]=b.x; r[5]=b.y; r[6]=b.z;  r[7]=b.w;
    r[8]=c.x; r[9]=c.y; r[10]=c.z; r[11]=c.w;
}

__device__ __forceinline__ void conv_body(const float* __restrict__ inp,
                                          const float* __restrict__ wv, float* acc) {
    float rb[3][12];
    load_row(inp, rb[0]);
    load_row(inp + 12, rb[1]);
#pragma unroll
    for (int oy = 0; oy < 9; oy++) {
        load_row(inp + (oy + 2) * 12, rb[(oy + 2) % 3]);
#pragma unroll
        for (int ky = 0; ky < 3; ky++) {
            const float* r = rb[(oy + ky) % 3];
#pragma unroll
            for (int ox = 0; ox < 9; ox++) {
                float s = acc[oy * 9 + ox];
                s = fmaf(r[ox + 0], wv[ky * 3 + 0], s);
                s = fmaf(r[ox + 1], wv[ky * 3 + 1], s);
                s = fmaf(r[ox + 2], wv[ky * 3 + 2], s);
                acc[oy * 9 + ox] = s;
            }
        }
    }
}

__global__ __launch_bounds__(128) void conv1_kernel(const float* __restrict__ xin,
        const float* __restrict__ wt, const float* __restrict__ bias,
        bf16* __restrict__ xout, float* __restrict__ sacc) {
    __shared__ __align__(16) float lds[4 * 3 * 132];
    __shared__ float Sl[128], Ql[128];
    int t = threadIdx.x;
    int img0 = blockIdx.x * 4;
    for (int i = t; i < 4 * 3 * 132; i += 128) lds[i] = 0.f;
    __syncthreads();
    const float* src = xin + (size_t)img0 * 243;
    for (int i = t; i < 4 * 243; i += 128) {
        int il = i / 243, rem = i - il * 243;
        int ci = rem / 81, px = rem - ci * 81;
        lds[(il * 3 + ci) * 132 + (px / 9 + 1) * 12 + (px % 9) + 1] = src[i];
    }
    __syncthreads();
    int oc = t & 31, il = t >> 5;
    const float* base = lds + il * 3 * 132;
    float acc[81];
    float bb = bias[oc];
#pragma unroll
    for (int i = 0; i < 81; i++) acc[i] = bb;
#pragma unroll
    for (int ci = 0; ci < 3; ci++) {
        float wv[9];
#pragma unroll
        for (int k = 0; k < 9; k++) wv[k] = wt[(ci * 9 + k) * 32 + oc];
        conv_body(base + ci * 132, wv, acc);
    }
    bf16* dst = xout + (size_t)(img0 + il) * (PXP * 32) + oc;
    float s = 0.f, q = 0.f;
#pragma unroll
    for (int p = 0; p < 81; p++) {
        float v = acc[p];
        s += v; q = fmaf(v, v, q);
        dst[p * 32] = __float2bfloat16(v);
    }
    dst[81 * 32] = __float2bfloat16(0.f);   // zero pad slot
    Sl[il * 32 + oc] = s;
    Ql[il * 32 + oc] = q;
    __syncthreads();
    if (t < 32)
        atomicAdd(&sacc[t], Sl[t] + Sl[32 + t] + Sl[64 + t] + Sl[96 + t]);
    else if (t < 64) {
        int c = t - 32;
        atomicAdd(&sacc[32 + c], Ql[c] + Ql[32 + c] + Ql[64 + c] + Ql[96 + c]);
    }
}

// ---------------- LDS-staged MFMA conv, zero-pad taps, fused stats ---------
// xin: post-BN bf16 [img][82][CI] (slot 81 = 0); wm: bf16 [oc][9tap][CI];
// out pre-BN bf16 [img][PXO][COT] (PXO=82 -> writes zero pad slot).
// Block: 256 imgs x 64 oc x 1 pixel. Grid = 8 xcd * (4 igl * 81 p * OCS).
template <int CI, int COT, int OCS, int PXO>
__global__ __launch_bounds__(256, 2) void conv_tile(const bf16* __restrict__ xin,
        const bf16* __restrict__ wm, const float* __restrict__ bias,
        bf16* __restrict__ xout, float* __restrict__ sacc) {
    constexpr int NCH = CI / 32;
    constexpr int ROW = 9 * CI;
    constexpr int STEPS = 9 * NCH;
    constexpr int PHASES = STEPS / 9;      // conv2: 1, conv3: 2
    constexpr int HS = STEPS / PHASES;     // 9 steps per phase
    // fragment-ordered: Bs[((sl*4+nf)*64+lane)*8]; wave read = contiguous 1KB
    __shared__ bf16 Bs[HS * 4 * 64 * 8];
    __shared__ float Ss[2][4][64];

    const int lin = blockIdx.x;
    const int xcd = lin & 7;
    const int slot = lin >> 3;
    constexpr int PSL = 81 * OCS;
    const int igl = slot / PSL;
    const int rem = slot - igl * PSL;
    const int p = rem / OCS;
    const int ob = rem - p * OCS;
    const int ig = xcd * 4 + igl;          // 32 groups of 256 imgs
    const int oc0 = ob * 64;
    const int py = p / 9, pxx = p - py * 9;
    const int tid = threadIdx.x;
    const int lane = tid & 63, wv = tid >> 6;
    const int m = lane & 15, quad = lane >> 4;
    const long img0 = (long)ig * 256 + wv * 64;

    // invalid taps -> pixel slot 81 (guaranteed zero) — no select needed
    int qt[9];
#pragma unroll
    for (int t = 0; t < 9; t++) {
        int iy = py + t / 3 - 1, ix = pxx + (t % 3) - 1;
        bool v = ((unsigned)iy < 9u) && ((unsigned)ix < 9u);
        qt[t] = v ? iy * 9 + ix : 81;
    }

    f32x4 acc[4][4];
#pragma unroll
    for (int nf = 0; nf < 4; nf++) {
        float bb = bias[oc0 + nf * 16 + m];
#pragma unroll
        for (int ms = 0; ms < 4; ms++) {
            acc[ms][nf][0] = bb; acc[ms][nf][1] = bb;
            acc[ms][nf][2] = bb; acc[ms][nf][3] = bb;
        }
    }
    const bf16* ab[4];
#pragma unroll
    for (int ms = 0; ms < 4; ms++)
        ab[ms] = xin + (img0 + ms * 16 + m) * (PXP * CI) + quad * 8;

    const bf16* bsl = &Bs[lane * 8];

#pragma unroll
    for (int ph = 0; ph < PHASES; ph++) {
        __syncthreads();   // prior phase's reads complete before overwrite
        for (int i = tid; i < HS * 4 * 64; i += 256) {
            int l2 = i & 63, nf = (i >> 6) & 3, sl = i >> 8;
            int s = ph * HS + sl;
            int t = s / NCH, ch = s - t * NCH;
            int mm = l2 & 15, qq = l2 >> 4;
            *(bf16x8*)(&Bs[(size_t)i * 8]) =
                *(const bf16x8*)(wm + (size_t)(oc0 + nf * 16 + mm) * ROW + t * CI + ch * 32 + qq * 8);
        }
        __syncthreads();   // stage complete
#pragma unroll
        for (int sl = 0; sl < HS; sl++) {
            const int s = ph * HS + sl;
            const int t = s / NCH, ch = s - t * NCH;
            bf16x8 bfr[4];
#pragma unroll
            for (int nf = 0; nf < 4; nf++)
                bfr[nf] = *(const bf16x8*)(bsl + (sl * 4 + nf) * 512);
            bf16x8 a[4];
#pragma unroll
            for (int ms = 0; ms < 4; ms++)
                a[ms] = *(const bf16x8*)(ab[ms] + qt[t] * CI + ch * 32);
#pragma unroll
            for (int ms = 0; ms < 4; ms++)
#pragma unroll
                for (int nf = 0; nf < 4; nf++)
                    acc[ms][nf] = __builtin_amdgcn_mfma_f32_16x16x32_bf16(a[ms], bfr[nf], acc[ms][nf], 0, 0, 0);
        }
    }

    // stores: D col = lane&15 (oc), row = quad*4 + reg (img)
    bf16* orow = xout + (img0 + quad * 4) * ((size_t)PXO * COT) + (size_t)p * COT + oc0 + m;
#pragma unroll
    for (int ms = 0; ms < 4; ms++)
#pragma unroll
        for (int nf = 0; nf < 4; nf++)
#pragma unroll
            for (int r = 0; r < 4; r++)
                orow[(size_t)(ms * 16 + r) * (PXO * COT) + nf * 16] =
                    __float2bfloat16(acc[ms][nf][r]);
    if (PXO == PXP && p == 0) {   // p==0 blocks zero the pad slot (81)
        bf16 z = __float2bfloat16(0.f);
        bf16* prow = xout + (img0 + quad * 4) * ((size_t)PXO * COT) + (size_t)81 * COT + oc0 + m;
#pragma unroll
        for (int ms = 0; ms < 4; ms++)
#pragma unroll
            for (int nf = 0; nf < 4; nf++)
#pragma unroll
                for (int r = 0; r < 4; r++)
                    prow[(size_t)(ms * 16 + r) * (PXO * COT) + nf * 16] = z;
    }

    // fused BN stats: per-oc sum / sumsq over this block's outputs
    float ssum[4], sq[4];
#pragma unroll
    for (int nf = 0; nf < 4; nf++) {
        float s = 0.f, q = 0.f;
#pragma unroll
        for (int ms = 0; ms < 4; ms++)
#pragma unroll
            for (int r = 0; r < 4; r++) {
                float v = acc[ms][nf][r];
                s += v; q = fmaf(v, v, q);
            }
        s += __shfl_xor(s, 16); s += __shfl_xor(s, 32);
        q += __shfl_xor(q, 16); q += __shfl_xor(q, 32);
        ssum[nf] = s; sq[nf] = q;
    }
    if (lane < 16) {
#pragma unroll
        for (int nf = 0; nf < 4; nf++) {
            Ss[0][wv][nf * 16 + lane] = ssum[nf];
            Ss[1][wv][nf * 16 + lane] = sq[nf];
        }
    }
    __syncthreads();
    if (tid < 64) {
        float a = Ss[0][0][tid] + Ss[0][1][tid] + Ss[0][2][tid] + Ss[0][3][tid];
        atomicAdd(&sacc[oc0 + tid], a);
    } else if (tid < 128) {
        int c = tid - 64;
        float a = Ss[1][0][c] + Ss[1][1][c] + Ss[1][2][c] + Ss[1][3][c];
        atomicAdd(&sacc[COT + oc0 + c], a);
    }
}

// ---------------- encoder: M=8192, N=128, K=10368 (x3 unpadded) ------------
// Grid 512: xcd = lin&7 owns igl(8, 128-img groups) x {ks(4) x nh(2)}.
__global__ __launch_bounds__(256) void enc_mfma(const bf16* __restrict__ x3,
        const bf16* __restrict__ ewb, float* __restrict__ part) {
    const int lin = blockIdx.x;
    const int xcd = lin & 7;
    const int slot = lin >> 3;           // 0..63
    const int igl = slot >> 3;           // 0..7
    const int combo = slot & 7;
    const int ks = combo >> 1, nh = combo & 1;
    const int ig = xcd * 8 + igl;        // 64 groups of 128 imgs
    const int lane = threadIdx.x & 63, wv = threadIdx.x >> 6;
    const int m = lane & 15, quad = lane >> 4;
    const long img0 = (long)ig * 128 + wv * 32;

    f32x4 acc[2][4];
#pragma unroll
    for (int ms = 0; ms < 2; ms++)
#pragma unroll
        for (int nf = 0; nf < 4; nf++) {
            acc[ms][nf][0]=0.f; acc[ms][nf][1]=0.f; acc[ms][nf][2]=0.f; acc[ms][nf][3]=0.f;
        }
    const bf16* ab[2];
    const bf16* bb[4];
#pragma unroll
    for (int ms = 0; ms < 2; ms++)
        ab[ms] = x3 + (img0 + ms * 16 + m) * FLAT + ks * 2592 + quad * 8;
#pragma unroll
    for (int nf = 0; nf < 4; nf++)
        bb[nf] = ewb + (size_t)(nh * 64 + nf * 16 + m) * FLAT + ks * 2592 + quad * 8;

#pragma unroll 3
    for (int c = 0; c < 81; c++) {
        bf16x8 Ac[2], Bc[4];
#pragma unroll
        for (int ms = 0; ms < 2; ms++) Ac[ms] = *(const bf16x8*)(ab[ms] + c * 32);
#pragma unroll
        for (int nf = 0; nf < 4; nf++) Bc[nf] = *(const bf16x8*)(bb[nf] + c * 32);
#pragma unroll
        for (int nf = 0; nf < 4; nf++)
#pragma unroll
            for (int ms = 0; ms < 2; ms++)
                acc[ms][nf] = __builtin_amdgcn_mfma_f32_16x16x32_bf16(Ac[ms], Bc[nf], acc[ms][nf], 0, 0, 0);
    }

    float* pp = part + (size_t)ks * (NIMG * 128) + (img0 + quad * 4) * 128 + nh * 64 + m;
#pragma unroll
    for (int ms = 0; ms < 2; ms++)
#pragma unroll
        for (int nf = 0; nf < 4; nf++)
#pragma unroll
            for (int r = 0; r < 4; r++)
                pp[(ms * 16 + r) * 128 + nf * 16] = acc[ms][nf][r];
}

template <int CO>
__global__ void stats_fin(const float* __restrict__ acc, const float* __restrict__ gamma,
                          const float* __restrict__ beta, float* __restrict__ st) {
    int c = threadIdx.x;
    if (c < CO) {
        const float inv = 1.0f / (8192.0f * 81.0f);
        float m = acc[c] * inv;
        float var = acc[CO + c] * inv - m * m;
        float istd = rsqrtf(var + 1e-5f);
        float sc = istd * gamma[c];
        st[c] = sc;
        st[CO + c] = beta[c] - m * sc;
    }
}

// ------- in-place BN+relu apply on bf16 [rows][CO]; PX=82 keeps pad=0 ------
template <int CO, int PX>
__global__ __launch_bounds__(256) void bn_apply(bf16* __restrict__ x,
                                                const float* __restrict__ st) {
    constexpr int CH8 = CO / 8;
    const int tid = blockIdx.x * 256 + threadIdx.x;
    const int stride = gridDim.x * 256;
    const int ci0 = (tid * 8) % CO;
    float sc[8], sh[8];
#pragma unroll
    for (int j = 0; j < 8; j++) { sc[j] = st[ci0 + j]; sh[j] = st[CO + ci0 + j]; }
    const int TOT8 = NIMG * PX * CO / 8;
    uint4* xp = (uint4*)x;
    for (int i = tid; i < TOT8; i += stride) {
        uint4 u = xp[i];
        bool pad = (PX == PXP) && ((i / CH8) % PX >= 81);
        float v[8] = {bflo(u.x), bfhi(u.x), bflo(u.y), bfhi(u.y),
                      bflo(u.z), bfhi(u.z), bflo(u.w), bfhi(u.w)};
        unsigned short us[8];
#pragma unroll
        for (int j = 0; j < 8; j++)
            us[j] = pad ? (unsigned short)0 : f2bf(fmaxf(fmaf(v[j], sc[j], sh[j]), 0.f));
        uint4 o;
        o.x = us[0] | ((unsigned)us[1] << 16);
        o.y = us[2] | ((unsigned)us[3] << 16);
        o.z = us[4] | ((unsigned)us[5] << 16);
        o.w = us[6] | ((unsigned)us[7] << 16);
        xp[i] = o;
    }
}

__global__ void enc_reduce(const float* __restrict__ part, const float* __restrict__ encb,
                           float* __restrict__ xE) {
    int i = blockIdx.x * 256 + threadIdx.x;
    const int NP = NIMG * 128;
    if (i < NP)
        xE[i] = part[i] + part[NP + i] + part[2 * NP + i] + part[3 * NP + i] + encb[i & 127];
}

// xT[b][f][n] = xE[b*128+n][f]
__global__ __launch_bounds__(256) void transpose_xe(const float* __restrict__ xE,
                                                    float* __restrict__ xT) {
    int b = blockIdx.x, t = threadIdx.x;
    const float* src = xE + (size_t)b * 16384;
    float* dst = xT + (size_t)b * 16384;
    for (int i = t; i < 16384; i += 256) {
        int n = i & 127, f = i >> 7;
        dst[i] = src[n * 128 + f];
    }
}

// Y[b] = A[b] (128x128) @ S[b] (128x128)
__global__ __launch_bounds__(256) void mm_xs(const float* __restrict__ A,
        const float* __restrict__ S, float* __restrict__ Y) {
    __shared__ __align__(16) float Sc[32 * 132];
    __shared__ float Acm[32 * 33];
    int b = blockIdx.y, f0 = blockIdx.x * 32;
    int t = threadIdx.x;
    int fl = t & 31, mg = t >> 5;
    const float* Ab = A + (size_t)b * 16384;
    const float* Sb = S + (size_t)b * 16384;
    float acc[16];
#pragma unroll
    for (int j = 0; j < 16; j++) acc[j] = 0.f;
    for (int nc = 0; nc < 128; nc += 32) {
#pragma unroll
        for (int r = 0; r < 4; r++) {
            int i4 = r * 256 + t;
            int nn = i4 >> 5, m4 = (i4 & 31) * 4;
            *(float4*)&Sc[nn * 132 + m4] = *(const float4*)&Sb[(size_t)(nc + nn) * 128 + m4];
        }
#pragma unroll
        for (int r = 0; r < 4; r++) {
            int i = r * 256 + t;
            int ff = i >> 5, nn = i & 31;
            Acm[ff * 33 + nn] = Ab[(size_t)(f0 + ff) * 128 + nc + nn];
        }
        __syncthreads();
#pragma unroll 4
        for (int nn = 0; nn < 32; nn++) {
            float a = Acm[fl * 33 + nn];
#pragma unroll
            for (int j = 0; j < 4; j++) {
                float4 s4 = *(const float4*)&Sc[nn * 132 + mg * 16 + j * 4];
                acc[j*4+0] = fmaf(a, s4.x, acc[j*4+0]);
                acc[j*4+1] = fmaf(a, s4.y, acc[j*4+1]);
                acc[j*4+2] = fmaf(a, s4.z, acc[j*4+2]);
                acc[j*4+3] = fmaf(a, s4.w, acc[j*4+3]);
            }
        }
        __syncthreads();
    }
    float* yb = Y + (size_t)b * 16384 + (size_t)(f0 + fl) * 128 + mg * 16;
#pragma unroll
    for (int j = 0; j < 4; j++)
        *(float4*)&yb[j * 4] = make_float4(acc[j*4], acc[j*4+1], acc[j*4+2], acc[j*4+3]);
}

// Out[b][g][n] = relu( sum_f W0[g,f]Z0 + W1 Z1 + W2 Z2 + bias[g] )
__global__ __launch_bounds__(256) void gf_combine(const float* __restrict__ Z0,
        const float* __restrict__ Z1, const float* __restrict__ Z2,
        const float* __restrict__ W, const float* __restrict__ bias,
        float* __restrict__ out) {
    __shared__ __align__(16) float Zc[32 * 132];
    __shared__ float Wc[32 * 33];
    int b = blockIdx.y, g0 = blockIdx.x * 32;
    int t = threadIdx.x;
    int gl = t & 31, mg = t >> 5;
    float acc[16];
    float bb = bias[g0 + gl];
#pragma unroll
    for (int j = 0; j < 16; j++) acc[j] = bb;
    const float* Zs[3] = {Z0 + (size_t)b * 16384, Z1 + (size_t)b * 16384, Z2 + (size_t)b * 16384};
    for (int j3 = 0; j3 < 3; j3++) {
        const float* Zb = Zs[j3];
        const float* Wj = W + j3 * 16384;
        for (int fc = 0; fc < 128; fc += 32) {
#pragma unroll
            for (int r = 0; r < 4; r++) {
                int i4 = r * 256 + t;
                int ff = i4 >> 5, m4 = (i4 & 31) * 4;
                *(float4*)&Zc[ff * 132 + m4] = *(const float4*)&Zb[(size_t)(fc + ff) * 128 + m4];
            }
#pragma unroll
            for (int r = 0; r < 4; r++) {
                int i = r * 256 + t;
                int gg = i >> 5, ff = i & 31;
                Wc[gg * 33 + ff] = Wj[(size_t)(g0 + gg) * 128 + fc + ff];
            }
            __syncthreads();
#pragma unroll 4
            for (int ff = 0; ff < 32; ff++) {
                float w = Wc[gl * 33 + ff];
#pragma unroll
                for (int j = 0; j < 4; j++) {
                    float4 z4 = *(const float4*)&Zc[ff * 132 + mg * 16 + j * 4];
                    acc[j*4+0] = fmaf(w, z4.x, acc[j*4+0]);
                    acc[j*4+1] = fmaf(w, z4.y, acc[j*4+1]);
                    acc[j*4+2] = fmaf(w, z4.z, acc[j*4+2]);
                    acc[j*4+3] = fmaf(w, z4.w, acc[j*4+3]);
                }
            }
            __syncthreads();
        }
    }
    float* ob = out + (size_t)b * 16384 + (size_t)(g0 + gl) * 128 + mg * 16;
#pragma unroll
    for (int j = 0; j < 4; j++)
        *(float4*)&ob[j * 4] = make_float4(fmaxf(acc[j*4], 0.f), fmaxf(acc[j*4+1], 0.f),
                                           fmaxf(acc[j*4+2], 0.f), fmaxf(acc[j*4+3], 0.f));
}

// logits[b,n,a] = sum_g X[b][g][n] * aw[a][g] + ab[a]
__global__ __launch_bounds__(128) void act_kernel(const float* __restrict__ X,
        const float* __restrict__ aw, const float* __restrict__ ab,
        float* __restrict__ out) {
    int b = blockIdx.x, n = threadIdx.x;
    float acc[5];
#pragma unroll
    for (int a = 0; a < 5; a++) acc[a] = ab[a];
    const float* xb = X + (size_t)b * 16384 + n;
#pragma unroll 4
    for (int g = 0; g < 128; g++) {
        float v = xb[(size_t)g * 128];
#pragma unroll
        for (int a = 0; a < 5; a++) acc[a] = fmaf(v, aw[a * 128 + g], acc[a]);
    }
    float* ob = out + ((size_t)b * 128 + n) * 5;
#pragma unroll
    for (int a = 0; a < 5; a++) ob[a] = acc[a];
}

// ---------------------------------------------------------------------------
extern "C" void kernel_launch(void* const* d_in, const int* in_sizes, int n_in,
                              void* d_out, int out_size, void* d_ws, size_t ws_size,
                              hipStream_t stream) {
    const float* states = (const float*)d_in[0];
    const float* gso    = (const float*)d_in[1];
    const float* c1w  = (const float*)d_in[2];
    const float* c1b  = (const float*)d_in[3];
    const float* c1g  = (const float*)d_in[4];
    const float* c1be = (const float*)d_in[5];
    const float* c2w  = (const float*)d_in[6];
    const float* c2b  = (const float*)d_in[7];
    const float* c2g  = (const float*)d_in[8];
    const float* c2be = (const float*)d_in[9];
    const float* c3w  = (const float*)d_in[10];
    const float* c3b  = (const float*)d_in[11];
    const float* c3g  = (const float*)d_in[12];
    const float* c3be = (const float*)d_in[13];
    const float* encw = (const float*)d_in[14];
    const float* encb = (const float*)d_in[15];
    const float* g1w  = (const float*)d_in[16];
    const float* g1b  = (const float*)d_in[17];
    const float* g2w  = (const float*)d_in[18];
    const float* g2b  = (const float*)d_in[19];
    const float* aw   = (const float*)d_in[20];
    const float* ab   = (const float*)d_in[21];
    float* out = (float*)d_out;
    char* ws = (char*)d_ws;

    size_t o = 0;
    auto take = [&](size_t bytes) { size_t r = o; o += (bytes + 255) & ~(size_t)255; return r; };
    const size_t o_x3  = take((size_t)NIMG * 81 * 128 * 2);    // 169,869,312 (unpadded)
    const size_t o_x2  = take((size_t)NIMG * PXP * 64 * 2);    //  85,983,232 (padded)
    const size_t o_w1t = take(27 * 32 * 4);
    const size_t o_w2m = take(64 * 288 * 2);
    const size_t o_w3m = take(128 * 576 * 2);
    const size_t o_acc = take(448 * 4);
    const size_t o_st1 = take(2 * 32 * 4);
    const size_t o_st2 = take(2 * 64 * 4);
    const size_t o_st3 = take(2 * 128 * 4);
    if (ws_size < o) {
        fill_sentinel<<<(out_size + 255) / 256, 256, 0, stream>>>(out, out_size);
        return;
    }

    const size_t o_x1 = o_x3;                       // x1 padded (43.0MB) at head of x3
    const size_t o_ewb  = o_x2;                     // 2,654,208 (aliases dead x2)
    const size_t o_part = o_x2 + 2654208;           // 16,777,216 (4 k-split partials)
    const size_t o_xE   = o_part + 16777216;
    const size_t o_xT   = o_xE + 4194304;
    const size_t o_y1   = o_xT + 4194304;
    const size_t o_y2   = o_y1 + 4194304;
    const size_t o_G1   = o_y2 + 4194304;
    const size_t o_G2   = o_G1 + 4194304;           // ends ~44.6MB < 86MB region

    bf16* x1 = (bf16*)(ws + o_x1);
    bf16* x2 = (bf16*)(ws + o_x2);
    bf16* x3 = (bf16*)(ws + o_x3);
    float* w1t = (float*)(ws + o_w1t);
    bf16* w2m = (bf16*)(ws + o_w2m);
    bf16* w3m = (bf16*)(ws + o_w3m);
    float* acc1 = (float*)(ws + o_acc);
    float* acc2 = acc1 + 64;
    float* acc3 = acc1 + 192;
    float* st1 = (float*)(ws + o_st1);
    float* st2 = (float*)(ws + o_st2);
    float* st3 = (float*)(ws + o_st3);
    bf16* ewb = (bf16*)(ws + o_ewb);
    float* partp = (float*)(ws + o_part);
    float* xE = (float*)(ws + o_xE);
    float* xT = (float*)(ws + o_xT);
    float* y1 = (float*)(ws + o_y1);
    float* y2 = (float*)(ws + o_y2);
    float* xG1 = (float*)(ws + o_G1);
    float* xG2 = (float*)(ws + o_G2);

    hipMemsetAsync(ws + o_acc, 0, 448 * 4, stream);
    prep_w<<<128, 256, 0, stream>>>(c1w, c2w, c3w, w1t, w2m, w3m);

    conv1_kernel<<<2048, 128, 0, stream>>>(states, w1t, c1b, x1, acc1);
    stats_fin<32><<<1, 32, 0, stream>>>(acc1, c1g, c1be, st1);
    bn_apply<32, PXP><<<2048, 256, 0, stream>>>(x1, st1);

    conv_tile<32, 64, 1, PXP><<<2592, 256, 0, stream>>>(x1, w2m, c2b, x2, acc2);
    stats_fin<64><<<1, 64, 0, stream>>>(acc2, c2g, c2be, st2);
    bn_apply<64, PXP><<<2048, 256, 0, stream>>>(x2, st2);

    conv_tile<64, 128, 2, 81><<<5184, 256, 0, stream>>>(x2, w3m, c3b, x3, acc3);
    stats_fin<128><<<1, 128, 0, stream>>>(acc3, c3g, c3be, st3);
    bn_apply<128, 81><<<2048, 256, 0, stream>>>(x3, st3);

    prep_enc<<<2048, 256, 0, stream>>>(encw, ewb);
    enc_mfma<<<512, 256, 0, stream>>>(x3, ewb, partp);
    enc_reduce<<<4096, 256, 0, stream>>>(partp, encb, xE);
    transpose_xe<<<64, 256, 0, stream>>>(xE, xT);

    mm_xs<<<dim3(4, 64), 256, 0, stream>>>(xT, gso, y1);
    mm_xs<<<dim3(4, 64), 256, 0, stream>>>(y1, gso, y2);
    gf_combine<<<dim3(4, 64), 256, 0, stream>>>(xT, y1, y2, g1w, g1b, xG1);

    mm_xs<<<dim3(4, 64), 256, 0, stream>>>(xG1, gso, y1);
    mm_xs<<<dim3(4, 64), 256, 0, stream>>>(y1, gso, y2);
    gf_combine<<<dim3(4, 64), 256, 0, stream>>>(xG1, y1, y2, g2w, g2b, xG2);

    act_kernel<<<64, 128, 0, stream>>>(xG2, aw, ab, out);
}

// Round 13
// 869.200 us; speedup vs baseline: 1.0126x; 1.0126x over previous
//
#include <hip/hip_runtime.h>
#include <hip/hip_bf16.h>
#include <stdint.h>

// ---------------------------------------------------------------------------
// Network_60163901882451 — round 13: conv_tile v8 — activation transpose.
// Activations stored [px][img][ci] (img contiguous): an MFMA A-frag load is
// 16 consecutive imgs x 64B = ONE contiguous 1KB wave access (4 cache lines),
// vs r12's 16 scattered 64B lines 10.5KB apart. Weights-in-LDS (fragment-
// ordered, 2-phase), fused BN stats, zero-pad pixel slot all unchanged.
// ---------------------------------------------------------------------------

#define NIMG 8192
#define NPIX 81
#define PXP 82
#define FLAT 10368

typedef __hip_bfloat16 bf16;
typedef short bf16x8 __attribute__((ext_vector_type(8)));
typedef float f32x4 __attribute__((ext_vector_type(4)));

__device__ __forceinline__ float bflo(unsigned u) { return __uint_as_float(u << 16); }
__device__ __forceinline__ float bfhi(unsigned u) { return __uint_as_float(u & 0xffff0000u); }
__device__ __forceinline__ unsigned short f2bf(float f) {
    unsigned u = __float_as_uint(f);
    return (unsigned short)((u + 0x7fff + ((u >> 16) & 1)) >> 16);
}

__global__ void fill_sentinel(float* __restrict__ out, int n) {
    int i = blockIdx.x * 256 + threadIdx.x;
    if (i < n) out[i] = 1.0e9f;   // ws_size-too-small signature
}

// ---------------- weight preps ---------------------------------------------
__global__ void prep_w(const float* __restrict__ c1w, const float* __restrict__ c2w,
                       const float* __restrict__ c3w,
                       float* __restrict__ w1t, bf16* __restrict__ w2m,
                       bf16* __restrict__ w3m) {
    int i0 = blockIdx.x * blockDim.x + threadIdx.x;
    int stride = gridDim.x * blockDim.x;
    for (int i = i0; i < 27 * 32; i += stride) w1t[i] = c1w[(i & 31) * 27 + (i >> 5)];
    for (int i = i0; i < 64 * 288; i += stride) {
        int oc = i / 288, r = i - oc * 288, t = r >> 5, ci = r & 31;
        w2m[i] = __float2bfloat16(c2w[oc * 288 + ci * 9 + t]);
    }
    for (int i = i0; i < 128 * 576; i += stride) {
        int oc = i / 576, r = i - oc * 576, t = r >> 6, ci = r & 63;
        w3m[i] = __float2bfloat16(c3w[oc * 576 + ci * 9 + t]);
    }
}

// ewb[e][px*128+ci] = encw[e][ci*81+px]
__global__ void prep_enc(const float* __restrict__ encw, bf16* __restrict__ ewb) {
    int i0 = blockIdx.x * blockDim.x + threadIdx.x;
    int stride = gridDim.x * blockDim.x;
    for (int i = i0; i < 128 * FLAT; i += stride) {
        int e = i / FLAT, r = i - e * FLAT;
        int px = r >> 7, ci = r & 127;
        ewb[i] = __float2bfloat16(encw[(size_t)e * FLAT + ci * 81 + px]);
    }
}

// ---------------- conv1 (direct fp32; fused stats; [px][img][32] out) ------
__device__ __forceinline__ void load_row(const float* __restrict__ p, float* r) {
    float4 a = *(const float4*)p;
    float4 b = *(const float4*)(p + 4);
    float4 c = *(const float4*)(p + 8);
    r[0]=a.x; r[1]=a.y; r[2]=a.z;  r[3]=a.w;
    r[4]=b.x; r[5]=b.y; r[6]=b.z;  r[7]=b.w;
    r[8]=c.x; r[9]=c.y; r[10]=c.z; r[11]=c.w;
}

__device__ __forceinline__ void conv_body(const float* __restrict__ inp,
                                          const float* __restrict__ wv, float* acc) {
    float rb[3][12];
    load_row(inp, rb[0]);
    load_row(inp + 12, rb[1]);
#pragma unroll
    for (int oy = 0; oy < 9; oy++) {
        load_row(inp + (oy + 2) * 12, rb[(oy + 2) % 3]);
#pragma unroll
        for (int ky = 0; ky < 3; ky++) {
            const float* r = rb[(oy + ky) % 3];
#pragma unroll
            for (int ox = 0; ox < 9; ox++) {
                float s = acc[oy * 9 + ox];
                s = fmaf(r[ox + 0], wv[ky * 3 + 0], s);
                s = fmaf(r[ox + 1], wv[ky * 3 + 1], s);
                s = fmaf(r[ox + 2], wv[ky * 3 + 2], s);
                acc[oy * 9 + ox] = s;
            }
        }
    }
}

__global__ __launch_bounds__(128) void conv1_kernel(const float* __restrict__ xin,
        const float* __restrict__ wt, const float* __restrict__ bias,
        bf16* __restrict__ xout, float* __restrict__ sacc) {
    __shared__ __align__(16) float lds[4 * 3 * 132];
    __shared__ float Sl[128], Ql[128];
    int t = threadIdx.x;
    int img0 = blockIdx.x * 4;
    for (int i = t; i < 4 * 3 * 132; i += 128) lds[i] = 0.f;
    __syncthreads();
    const float* src = xin + (size_t)img0 * 243;
    for (int i = t; i < 4 * 243; i += 128) {
        int il = i / 243, rem = i - il * 243;
        int ci = rem / 81, px = rem - ci * 81;
        lds[(il * 3 + ci) * 132 + (px / 9 + 1) * 12 + (px % 9) + 1] = src[i];
    }
    __syncthreads();
    int oc = t & 31, il = t >> 5;
    const float* base = lds + il * 3 * 132;
    float acc[81];
    float bb = bias[oc];
#pragma unroll
    for (int i = 0; i < 81; i++) acc[i] = bb;
#pragma unroll
    for (int ci = 0; ci < 3; ci++) {
        float wv[9];
#pragma unroll
        for (int k = 0; k < 9; k++) wv[k] = wt[(ci * 9 + k) * 32 + oc];
        conv_body(base + ci * 132, wv, acc);
    }
    // out: [px][img][32]
    bf16* dst = xout + (size_t)(img0 + il) * 32 + oc;
    const size_t PXS = (size_t)NIMG * 32;
    float s = 0.f, q = 0.f;
#pragma unroll
    for (int p = 0; p < 81; p++) {
        float v = acc[p];
        s += v; q = fmaf(v, v, q);
        dst[p * PXS] = __float2bfloat16(v);
    }
    dst[81 * PXS] = __float2bfloat16(0.f);   // zero pad slot
    Sl[il * 32 + oc] = s;
    Ql[il * 32 + oc] = q;
    __syncthreads();
    if (t < 32)
        atomicAdd(&sacc[t], Sl[t] + Sl[32 + t] + Sl[64 + t] + Sl[96 + t]);
    else if (t < 64) {
        int c = t - 32;
        atomicAdd(&sacc[32 + c], Ql[c] + Ql[32 + c] + Ql[64 + c] + Ql[96 + c]);
    }
}

// ---------------- LDS-staged MFMA conv, [px][img][ci] activations ----------
// xin: post-BN bf16 [82][NIMG][CI] (slot 81 = 0); wm: bf16 [oc][9tap][CI];
// out pre-BN bf16 [PXO][NIMG][COT]. Block: 256 imgs x 64 oc x 1 pixel.
template <int CI, int COT, int OCS, bool PADOUT>
__global__ __launch_bounds__(256, 2) void conv_tile(const bf16* __restrict__ xin,
        const bf16* __restrict__ wm, const float* __restrict__ bias,
        bf16* __restrict__ xout, float* __restrict__ sacc) {
    constexpr int NCH = CI / 32;
    constexpr int ROW = 9 * CI;
    constexpr int STEPS = 9 * NCH;
    constexpr int PHASES = STEPS / 9;      // conv2: 1, conv3: 2
    constexpr int HS = STEPS / PHASES;     // 9 steps per phase
    constexpr size_t PXS = (size_t)NIMG * CI;   // input pixel-slot stride
    constexpr size_t PXSO = (size_t)NIMG * COT; // output pixel-slot stride
    __shared__ bf16 Bs[HS * 4 * 64 * 8];
    __shared__ float Ss[2][4][64];

    const int lin = blockIdx.x;
    const int xcd = lin & 7;
    const int slot = lin >> 3;
    constexpr int PSL = 81 * OCS;
    const int igl = slot / PSL;
    const int rem = slot - igl * PSL;
    const int p = rem / OCS;
    const int ob = rem - p * OCS;
    const int ig = xcd * 4 + igl;          // 32 groups of 256 imgs
    const int oc0 = ob * 64;
    const int py = p / 9, pxx = p - py * 9;
    const int tid = threadIdx.x;
    const int lane = tid & 63, wv = tid >> 6;
    const int m = lane & 15, quad = lane >> 4;
    const long img0 = (long)ig * 256 + wv * 64;

    // invalid taps -> pixel slot 81 (guaranteed zero)
    int qt[9];
#pragma unroll
    for (int t = 0; t < 9; t++) {
        int iy = py + t / 3 - 1, ix = pxx + (t % 3) - 1;
        bool v = ((unsigned)iy < 9u) && ((unsigned)ix < 9u);
        qt[t] = v ? iy * 9 + ix : 81;
    }

    f32x4 acc[4][4];
#pragma unroll
    for (int nf = 0; nf < 4; nf++) {
        float bb = bias[oc0 + nf * 16 + m];
#pragma unroll
        for (int ms = 0; ms < 4; ms++) {
            acc[ms][nf][0] = bb; acc[ms][nf][1] = bb;
            acc[ms][nf][2] = bb; acc[ms][nf][3] = bb;
        }
    }
    // A base per ms: [px][img][ci] -> contiguous 1KB per wave-load
    const bf16* ab[4];
#pragma unroll
    for (int ms = 0; ms < 4; ms++)
        ab[ms] = xin + (img0 + ms * 16 + m) * CI + quad * 8;

    const bf16* bsl = &Bs[lane * 8];

#pragma unroll
    for (int ph = 0; ph < PHASES; ph++) {
        __syncthreads();
        for (int i = tid; i < HS * 4 * 64; i += 256) {
            int l2 = i & 63, nf = (i >> 6) & 3, sl = i >> 8;
            int s = ph * HS + sl;
            int t = s / NCH, ch = s - t * NCH;
            int mm = l2 & 15, qq = l2 >> 4;
            *(bf16x8*)(&Bs[(size_t)i * 8]) =
                *(const bf16x8*)(wm + (size_t)(oc0 + nf * 16 + mm) * ROW + t * CI + ch * 32 + qq * 8);
        }
        __syncthreads();
#pragma unroll
        for (int sl = 0; sl < HS; sl++) {
            const int s = ph * HS + sl;
            const int t = s / NCH, ch = s - t * NCH;
            bf16x8 bfr[4];
#pragma unroll
            for (int nf = 0; nf < 4; nf++)
                bfr[nf] = *(const bf16x8*)(bsl + (sl * 4 + nf) * 512);
            bf16x8 a[4];
#pragma unroll
            for (int ms = 0; ms < 4; ms++)
                a[ms] = *(const bf16x8*)(ab[ms] + (size_t)qt[t] * PXS + ch * 32);
#pragma unroll
            for (int ms = 0; ms < 4; ms++)
#pragma unroll
                for (int nf = 0; nf < 4; nf++)
                    acc[ms][nf] = __builtin_amdgcn_mfma_f32_16x16x32_bf16(a[ms], bfr[nf], acc[ms][nf], 0, 0, 0);
        }
    }

    // stores: [p][img][oc]; D col = lane&15 (oc), row = quad*4 + reg (img)
    bf16* orow = xout + (size_t)p * PXSO + (img0 + quad * 4) * COT + oc0 + m;
#pragma unroll
    for (int ms = 0; ms < 4; ms++)
#pragma unroll
        for (int nf = 0; nf < 4; nf++)
#pragma unroll
            for (int r = 0; r < 4; r++)
                orow[(size_t)(ms * 16 + r) * COT + nf * 16] =
                    __float2bfloat16(acc[ms][nf][r]);
    if (PADOUT && p == 0) {   // p==0 blocks zero the pad slot (81)
        bf16 z = __float2bfloat16(0.f);
        bf16* prow = xout + (size_t)81 * PXSO + (img0 + quad * 4) * COT + oc0 + m;
#pragma unroll
        for (int ms = 0; ms < 4; ms++)
#pragma unroll
            for (int nf = 0; nf < 4; nf++)
#pragma unroll
                for (int r = 0; r < 4; r++)
                    prow[(size_t)(ms * 16 + r) * COT + nf * 16] = z;
    }

    // fused BN stats
    float ssum[4], sq[4];
#pragma unroll
    for (int nf = 0; nf < 4; nf++) {
        float s = 0.f, q = 0.f;
#pragma unroll
        for (int ms = 0; ms < 4; ms++)
#pragma unroll
            for (int r = 0; r < 4; r++) {
                float v = acc[ms][nf][r];
                s += v; q = fmaf(v, v, q);
            }
        s += __shfl_xor(s, 16); s += __shfl_xor(s, 32);
        q += __shfl_xor(q, 16); q += __shfl_xor(q, 32);
        ssum[nf] = s; sq[nf] = q;
    }
    if (lane < 16) {
#pragma unroll
        for (int nf = 0; nf < 4; nf++) {
            Ss[0][wv][nf * 16 + lane] = ssum[nf];
            Ss[1][wv][nf * 16 + lane] = sq[nf];
        }
    }
    __syncthreads();
    if (tid < 64) {
        float a = Ss[0][0][tid] + Ss[0][1][tid] + Ss[0][2][tid] + Ss[0][3][tid];
        atomicAdd(&sacc[oc0 + tid], a);
    } else if (tid < 128) {
        int c = tid - 64;
        float a = Ss[1][0][c] + Ss[1][1][c] + Ss[1][2][c] + Ss[1][3][c];
        atomicAdd(&sacc[COT + oc0 + c], a);
    }
}

// ---------------- encoder: x3 = [81][NIMG][128]; K-split by px ranges ------
// Grid 512: xcd = lin&7 owns igl(8, 128-img groups) x {ks(4) x nh(2)}.
__global__ __launch_bounds__(256) void enc_mfma(const bf16* __restrict__ x3,
        const bf16* __restrict__ ewb, float* __restrict__ part) {
    const int lin = blockIdx.x;
    const int xcd = lin & 7;
    const int slot = lin >> 3;           // 0..63
    const int igl = slot >> 3;           // 0..7
    const int combo = slot & 7;
    const int ks = combo >> 1, nh = combo & 1;
    const int ig = xcd * 8 + igl;        // 64 groups of 128 imgs
    const int lane = threadIdx.x & 63, wv = threadIdx.x >> 6;
    const int m = lane & 15, quad = lane >> 4;
    const long img0 = (long)ig * 128 + wv * 32;
    const int pxbase = (ks == 0) ? 0 : (21 + 20 * (ks - 1));   // {0,21,41,61}
    const int pxcnt = (ks == 0) ? 21 : 20;

    f32x4 acc[2][4];
#pragma unroll
    for (int ms = 0; ms < 2; ms++)
#pragma unroll
        for (int nf = 0; nf < 4; nf++) {
            acc[ms][nf][0]=0.f; acc[ms][nf][1]=0.f; acc[ms][nf][2]=0.f; acc[ms][nf][3]=0.f;
        }
    const bf16* ab[2];
    const bf16* bb[4];
#pragma unroll
    for (int ms = 0; ms < 2; ms++)
        ab[ms] = x3 + ((size_t)pxbase * NIMG + img0 + ms * 16 + m) * 128 + quad * 8;
#pragma unroll
    for (int nf = 0; nf < 4; nf++)
        bb[nf] = ewb + (size_t)(nh * 64 + nf * 16 + m) * FLAT + pxbase * 128 + quad * 8;

    for (int px = 0; px < pxcnt; px++) {
#pragma unroll
        for (int cc = 0; cc < 4; cc++) {
            bf16x8 Ac[2], Bc[4];
#pragma unroll
            for (int ms = 0; ms < 2; ms++)
                Ac[ms] = *(const bf16x8*)(ab[ms] + (size_t)px * (NIMG * 128) + cc * 32);
#pragma unroll
            for (int nf = 0; nf < 4; nf++)
                Bc[nf] = *(const bf16x8*)(bb[nf] + px * 128 + cc * 32);
#pragma unroll
            for (int nf = 0; nf < 4; nf++)
#pragma unroll
                for (int ms = 0; ms < 2; ms++)
                    acc[ms][nf] = __builtin_amdgcn_mfma_f32_16x16x32_bf16(Ac[ms], Bc[nf], acc[ms][nf], 0, 0, 0);
        }
    }

    float* pp = part + (size_t)ks * (NIMG * 128) + (img0 + quad * 4) * 128 + nh * 64 + m;
#pragma unroll
    for (int ms = 0; ms < 2; ms++)
#pragma unroll
        for (int nf = 0; nf < 4; nf++)
#pragma unroll
            for (int r = 0; r < 4; r++)
                pp[(ms * 16 + r) * 128 + nf * 16] = acc[ms][nf][r];
}

template <int CO>
__global__ void stats_fin(const float* __restrict__ acc, const float* __restrict__ gamma,
                          const float* __restrict__ beta, float* __restrict__ st) {
    int c = threadIdx.x;
    if (c < CO) {
        const float inv = 1.0f / (8192.0f * 81.0f);
        float m = acc[c] * inv;
        float var = acc[CO + c] * inv - m * m;
        float istd = rsqrtf(var + 1e-5f);
        float sc = istd * gamma[c];
        st[c] = sc;
        st[CO + c] = beta[c] - m * sc;
    }
}

// ------- in-place BN+relu apply; [PX][NIMG][CO], pad slot (>=81) -> 0 ------
template <int CO, int PX>
__global__ __launch_bounds__(256) void bn_apply(bf16* __restrict__ x,
                                                const float* __restrict__ st) {
    constexpr int SLOT8 = NIMG * CO / 8;   // uint4-elements per pixel slot
    const int tid = blockIdx.x * 256 + threadIdx.x;
    const int stride = gridDim.x * 256;
    const int ci0 = (tid * 8) % CO;
    float sc[8], sh[8];
#pragma unroll
    for (int j = 0; j < 8; j++) { sc[j] = st[ci0 + j]; sh[j] = st[CO + ci0 + j]; }
    const int TOT8 = PX * SLOT8;
    uint4* xp = (uint4*)x;
    for (int i = tid; i < TOT8; i += stride) {
        uint4 u = xp[i];
        bool pad = (PX == PXP) && (i / SLOT8 >= 81);
        float v[8] = {bflo(u.x), bfhi(u.x), bflo(u.y), bfhi(u.y),
                      bflo(u.z), bfhi(u.z), bflo(u.w), bfhi(u.w)};
        unsigned short us[8];
#pragma unroll
        for (int j = 0; j < 8; j++)
            us[j] = pad ? (unsigned short)0 : f2bf(fmaxf(fmaf(v[j], sc[j], sh[j]), 0.f));
        uint4 o;
        o.x = us[0] | ((unsigned)us[1] << 16);
        o.y = us[2] | ((unsigned)us[3] << 16);
        o.z = us[4] | ((unsigned)us[5] << 16);
        o.w = us[6] | ((unsigned)us[7] << 16);
        xp[i] = o;
    }
}

__global__ void enc_reduce(const float* __restrict__ part, const float* __restrict__ encb,
                           float* __restrict__ xE) {
    int i = blockIdx.x * 256 + threadIdx.x;
    const int NP = NIMG * 128;
    if (i < NP)
        xE[i] = part[i] + part[NP + i] + part[2 * NP + i] + part[3 * NP + i] + encb[i & 127];
}

// xT[b][f][n] = xE[b*128+n][f]
__global__ __launch_bounds__(256) void transpose_xe(const float* __restrict__ xE,
                                                    float* __restrict__ xT) {
    int b = blockIdx.x, t = threadIdx.x;
    const float* src = xE + (size_t)b * 16384;
    float* dst = xT + (size_t)b * 16384;
    for (int i = t; i < 16384; i += 256) {
        int n = i & 127, f = i >> 7;
        dst[i] = src[n * 128 + f];
    }
}

// Y[b] = A[b] (128x128) @ S[b] (128x128)
__global__ __launch_bounds__(256) void mm_xs(const float* __restrict__ A,
        const float* __restrict__ S, float* __restrict__ Y) {
    __shared__ __align__(16) float Sc[32 * 132];
    __shared__ float Acm[32 * 33];
    int b = blockIdx.y, f0 = blockIdx.x * 32;
    int t = threadIdx.x;
    int fl = t & 31, mg = t >> 5;
    const float* Ab = A + (size_t)b * 16384;
    const float* Sb = S + (size_t)b * 16384;
    float acc[16];
#pragma unroll
    for (int j = 0; j < 16; j++) acc[j] = 0.f;
    for (int nc = 0; nc < 128; nc += 32) {
#pragma unroll
        for (int r = 0; r < 4; r++) {
            int i4 = r * 256 + t;
            int nn = i4 >> 5, m4 = (i4 & 31) * 4;
            *(float4*)&Sc[nn * 132 + m4] = *(const float4*)&Sb[(size_t)(nc + nn) * 128 + m4];
        }
#pragma unroll
        for (int r = 0; r < 4; r++) {
            int i = r * 256 + t;
            int ff = i >> 5, nn = i & 31;
            Acm[ff * 33 + nn] = Ab[(size_t)(f0 + ff) * 128 + nc + nn];
        }
        __syncthreads();
#pragma unroll 4
        for (int nn = 0; nn < 32; nn++) {
            float a = Acm[fl * 33 + nn];
#pragma unroll
            for (int j = 0; j < 4; j++) {
                float4 s4 = *(const float4*)&Sc[nn * 132 + mg * 16 + j * 4];
                acc[j*4+0] = fmaf(a, s4.x, acc[j*4+0]);
                acc[j*4+1] = fmaf(a, s4.y, acc[j*4+1]);
                acc[j*4+2] = fmaf(a, s4.z, acc[j*4+2]);
                acc[j*4+3] = fmaf(a, s4.w, acc[j*4+3]);
            }
        }
        __syncthreads();
    }
    float* yb = Y + (size_t)b * 16384 + (size_t)(f0 + fl) * 128 + mg * 16;
#pragma unroll
    for (int j = 0; j < 4; j++)
        *(float4*)&yb[j * 4] = make_float4(acc[j*4], acc[j*4+1], acc[j*4+2], acc[j*4+3]);
}

// Out[b][g][n] = relu( sum_f W0[g,f]Z0 + W1 Z1 + W2 Z2 + bias[g] )
__global__ __launch_bounds__(256) void gf_combine(const float* __restrict__ Z0,
        const float* __restrict__ Z1, const float* __restrict__ Z2,
        const float* __restrict__ W, const float* __restrict__ bias,
        float* __restrict__ out) {
    __shared__ __align__(16) float Zc[32 * 132];
    __shared__ float Wc[32 * 33];
    int b = blockIdx.y, g0 = blockIdx.x * 32;
    int t = threadIdx.x;
    int gl = t & 31, mg = t >> 5;
    float acc[16];
    float bb = bias[g0 + gl];
#pragma unroll
    for (int j = 0; j < 16; j++) acc[j] = bb;
    const float* Zs[3] = {Z0 + (size_t)b * 16384, Z1 + (size_t)b * 16384, Z2 + (size_t)b * 16384};
    for (int j3 = 0; j3 < 3; j3++) {
        const float* Zb = Zs[j3];
        const float* Wj = W + j3 * 16384;
        for (int fc = 0; fc < 128; fc += 32) {
#pragma unroll
            for (int r = 0; r < 4; r++) {
                int i4 = r * 256 + t;
                int ff = i4 >> 5, m4 = (i4 & 31) * 4;
                *(float4*)&Zc[ff * 132 + m4] = *(const float4*)&Zb[(size_t)(fc + ff) * 128 + m4];
            }
#pragma unroll
            for (int r = 0; r < 4; r++) {
                int i = r * 256 + t;
                int gg = i >> 5, ff = i & 31;
                Wc[gg * 33 + ff] = Wj[(size_t)(g0 + gg) * 128 + fc + ff];
            }
            __syncthreads();
#pragma unroll 4
            for (int ff = 0; ff < 32; ff++) {
                float w = Wc[gl * 33 + ff];
#pragma unroll
                for (int j = 0; j < 4; j++) {
                    float4 z4 = *(const float4*)&Zc[ff * 132 + mg * 16 + j * 4];
                    acc[j*4+0] = fmaf(w, z4.x, acc[j*4+0]);
                    acc[j*4+1] = fmaf(w, z4.y, acc[j*4+1]);
                    acc[j*4+2] = fmaf(w, z4.z, acc[j*4+2]);
                    acc[j*4+3] = fmaf(w, z4.w, acc[j*4+3]);
                }
            }
            __syncthreads();
        }
    }
    float* ob = out + (size_t)b * 16384 + (size_t)(g0 + gl) * 128 + mg * 16;
#pragma unroll
    for (int j = 0; j < 4; j++)
        *(float4*)&ob[j * 4] = make_float4(fmaxf(acc[j*4], 0.f), fmaxf(acc[j*4+1], 0.f),
                                           fmaxf(acc[j*4+2], 0.f), fmaxf(acc[j*4+3], 0.f));
}

// logits[b,n,a] = sum_g X[b][g][n] * aw[a][g] + ab[a]
__global__ __launch_bounds__(128) void act_kernel(const float* __restrict__ X,
        const float* __restrict__ aw, const float* __restrict__ ab,
        float* __restrict__ out) {
    int b = blockIdx.x, n = threadIdx.x;
    float acc[5];
#pragma unroll
    for (int a = 0; a < 5; a++) acc[a] = ab[a];
    const float* xb = X + (size_t)b * 16384 + n;
#pragma unroll 4
    for (int g = 0; g < 128; g++) {
        float v = xb[(size_t)g * 128];
#pragma unroll
        for (int a = 0; a < 5; a++) acc[a] = fmaf(v, aw[a * 128 + g], acc[a]);
    }
    float* ob = out + ((size_t)b * 128 + n) * 5;
#pragma unroll
    for (int a = 0; a < 5; a++) ob[a] = acc[a];
}

// ---------------------------------------------------------------------------
extern "C" void kernel_launch(void* const* d_in, const int* in_sizes, int n_in,
                              void* d_out, int out_size, void* d_ws, size_t ws_size,
                              hipStream_t stream) {
    const float* states = (const float*)d_in[0];
    const float* gso    = (const float*)d_in[1];
    const float* c1w  = (const float*)d_in[2];
    const float* c1b  = (const float*)d_in[3];
    const float* c1g  = (const float*)d_in[4];
    const float* c1be = (const float*)d_in[5];
    const float* c2w  = (const float*)d_in[6];
    const float* c2b  = (const float*)d_in[7];
    const float* c2g  = (const float*)d_in[8];
    const float* c2be = (const float*)d_in[9];
    const float* c3w  = (const float*)d_in[10];
    const float* c3b  = (const float*)d_in[11];
    const float* c3g  = (const float*)d_in[12];
    const float* c3be = (const float*)d_in[13];
    const float* encw = (const float*)d_in[14];
    const float* encb = (const float*)d_in[15];
    const float* g1w  = (const float*)d_in[16];
    const float* g1b  = (const float*)d_in[17];
    const float* g2w  = (const float*)d_in[18];
    const float* g2b  = (const float*)d_in[19];
    const float* aw   = (const float*)d_in[20];
    const float* ab   = (const float*)d_in[21];
    float* out = (float*)d_out;
    char* ws = (char*)d_ws;

    size_t o = 0;
    auto take = [&](size_t bytes) { size_t r = o; o += (bytes + 255) & ~(size_t)255; return r; };
    const size_t o_x3  = take((size_t)81 * NIMG * 128 * 2);    // 169,869,312
    const size_t o_x2  = take((size_t)PXP * NIMG * 64 * 2);    //  85,983,232
    const size_t o_w1t = take(27 * 32 * 4);
    const size_t o_w2m = take(64 * 288 * 2);
    const size_t o_w3m = take(128 * 576 * 2);
    const size_t o_acc = take(448 * 4);
    const size_t o_st1 = take(2 * 32 * 4);
    const size_t o_st2 = take(2 * 64 * 4);
    const size_t o_st3 = take(2 * 128 * 4);
    if (ws_size < o) {
        fill_sentinel<<<(out_size + 255) / 256, 256, 0, stream>>>(out, out_size);
        return;
    }

    const size_t o_x1 = o_x3;                       // x1 (43MB) at head of x3 region
    const size_t o_ewb  = o_x2;                     // 2,654,208 (aliases dead x2)
    const size_t o_part = o_x2 + 2654208;           // 16,777,216
    const size_t o_xE   = o_part + 16777216;
    const size_t o_xT   = o_xE + 4194304;
    const size_t o_y1   = o_xT + 4194304;
    const size_t o_y2   = o_y1 + 4194304;
    const size_t o_G1   = o_y2 + 4194304;
    const size_t o_G2   = o_G1 + 4194304;           // ends ~44.6MB < 86MB region

    bf16* x1 = (bf16*)(ws + o_x1);
    bf16* x2 = (bf16*)(ws + o_x2);
    bf16* x3 = (bf16*)(ws + o_x3);
    float* w1t = (float*)(ws + o_w1t);
    bf16* w2m = (bf16*)(ws + o_w2m);
    bf16* w3m = (bf16*)(ws + o_w3m);
    float* acc1 = (float*)(ws + o_acc);
    float* acc2 = acc1 + 64;
    float* acc3 = acc1 + 192;
    float* st1 = (float*)(ws + o_st1);
    float* st2 = (float*)(ws + o_st2);
    float* st3 = (float*)(ws + o_st3);
    bf16* ewb = (bf16*)(ws + o_ewb);
    float* partp = (float*)(ws + o_part);
    float* xE = (float*)(ws + o_xE);
    float* xT = (float*)(ws + o_xT);
    float* y1 = (float*)(ws + o_y1);
    float* y2 = (float*)(ws + o_y2);
    float* xG1 = (float*)(ws + o_G1);
    float* xG2 = (float*)(ws + o_G2);

    hipMemsetAsync(ws + o_acc, 0, 448 * 4, stream);
    prep_w<<<128, 256, 0, stream>>>(c1w, c2w, c3w, w1t, w2m, w3m);

    conv1_kernel<<<2048, 128, 0, stream>>>(states, w1t, c1b, x1, acc1);
    stats_fin<32><<<1, 32, 0, stream>>>(acc1, c1g, c1be, st1);
    bn_apply<32, PXP><<<2048, 256, 0, stream>>>(x1, st1);

    conv_tile<32, 64, 1, true><<<2592, 256, 0, stream>>>(x1, w2m, c2b, x2, acc2);
    stats_fin<64><<<1, 64, 0, stream>>>(acc2, c2g, c2be, st2);
    bn_apply<64, PXP><<<2048, 256, 0, stream>>>(x2, st2);

    conv_tile<64, 128, 2, false><<<5184, 256, 0, stream>>>(x2, w3m, c3b, x3, acc3);
    stats_fin<128><<<1, 128, 0, stream>>>(acc3, c3g, c3be, st3);
    bn_apply<128, 81><<<2048, 256, 0, stream>>>(x3, st3);

    prep_enc<<<2048, 256, 0, stream>>>(encw, ewb);
    enc_mfma<<<512, 256, 0, stream>>>(x3, ewb, partp);
    enc_reduce<<<4096, 256, 0, stream>>>(partp, encb, xE);
    transpose_xe<<<64, 256, 0, stream>>>(xE, xT);

    mm_xs<<<dim3(4, 64), 256, 0, stream>>>(xT, gso, y1);
    mm_xs<<<dim3(4, 64), 256, 0, stream>>>(y1, gso, y2);
    gf_combine<<<dim3(4, 64), 256, 0, stream>>>(xT, y1, y2, g1w, g1b, xG1);

    mm_xs<<<dim3(4, 64), 256, 0, stream>>>(xG1, gso, y1);
    mm_xs<<<dim3(4, 64), 256, 0, stream>>>(y1, gso, y2);
    gf_combine<<<dim3(4, 64), 256, 0, stream>>>(xG1, y1, y2, g2w, g2b, xG2);

    act_kernel<<<64, 128, 0, stream>>>(xG2, aw, ab, out);
}

// Round 14
// 796.927 us; speedup vs baseline: 1.1044x; 1.0907x over previous
//
#include <hip/hip_runtime.h>
#include <hip/hip_bf16.h>
#include <stdint.h>

// ---------------------------------------------------------------------------
// Network_60163901882451 — round 14: r11 conv structure (best measured) +
// BN/relu fused into consumers' A-paths (bn_apply kernels deleted, -700MB),
// transpose folded into enc_reduce. Convs: 2-phase fragment-ordered LDS
// weights, fused BN stats, vt-select (post-BN) for padding taps.
// ---------------------------------------------------------------------------

#define NIMG 8192
#define NPIX 81
#define FLAT 10368

typedef __hip_bfloat16 bf16;
typedef short bf16x8 __attribute__((ext_vector_type(8)));
typedef float f32x4 __attribute__((ext_vector_type(4)));

__device__ __forceinline__ float bflo(unsigned u) { return __uint_as_float(u << 16); }
__device__ __forceinline__ float bfhi(unsigned u) { return __uint_as_float(u & 0xffff0000u); }
__device__ __forceinline__ unsigned short f2bf(float f) {
    unsigned u = __float_as_uint(f);
    return (unsigned short)((u + 0x7fff + ((u >> 16) & 1)) >> 16);
}

// BN+relu on a bf16x8 fragment; sc/sh are per-element (ci-indexed) registers
__device__ __forceinline__ bf16x8 bn8(bf16x8 a, const float* sc, const float* sh) {
    union U { bf16x8 v; unsigned u[4]; } in, out;
    in.v = a;
#pragma unroll
    for (int d = 0; d < 4; d++) {
        float lo = fmaxf(fmaf(bflo(in.u[d]), sc[2 * d],     sh[2 * d]),     0.f);
        float hi = fmaxf(fmaf(bfhi(in.u[d]), sc[2 * d + 1], sh[2 * d + 1]), 0.f);
        out.u[d] = (unsigned)f2bf(lo) | ((unsigned)f2bf(hi) << 16);
    }
    return out.v;
}

__global__ void fill_sentinel(float* __restrict__ out, int n) {
    int i = blockIdx.x * 256 + threadIdx.x;
    if (i < n) out[i] = 1.0e9f;   // ws_size-too-small signature
}

// ---------------- weight preps ---------------------------------------------
__global__ void prep_w(const float* __restrict__ c1w, const float* __restrict__ c2w,
                       const float* __restrict__ c3w,
                       float* __restrict__ w1t, bf16* __restrict__ w2m,
                       bf16* __restrict__ w3m) {
    int i0 = blockIdx.x * blockDim.x + threadIdx.x;
    int stride = gridDim.x * blockDim.x;
    for (int i = i0; i < 27 * 32; i += stride) w1t[i] = c1w[(i & 31) * 27 + (i >> 5)];
    for (int i = i0; i < 64 * 288; i += stride) {
        int oc = i / 288, r = i - oc * 288, t = r >> 5, ci = r & 31;
        w2m[i] = __float2bfloat16(c2w[oc * 288 + ci * 9 + t]);
    }
    for (int i = i0; i < 128 * 576; i += stride) {
        int oc = i / 576, r = i - oc * 576, t = r >> 6, ci = r & 63;
        w3m[i] = __float2bfloat16(c3w[oc * 576 + ci * 9 + t]);
    }
}

// ewb[e][px*128+ci] = encw[e][ci*81+px]
__global__ void prep_enc(const float* __restrict__ encw, bf16* __restrict__ ewb) {
    int i0 = blockIdx.x * blockDim.x + threadIdx.x;
    int stride = gridDim.x * blockDim.x;
    for (int i = i0; i < 128 * FLAT; i += stride) {
        int e = i / FLAT, r = i - e * FLAT;
        int px = r >> 7, ci = r & 127;
        ewb[i] = __float2bfloat16(encw[(size_t)e * FLAT + ci * 81 + px]);
    }
}

// ---------------- conv1 (direct fp32; fused stats; raw out) ----------------
__device__ __forceinline__ void load_row(const float* __restrict__ p, float* r) {
    float4 a = *(const float4*)p;
    float4 b = *(const float4*)(p + 4);
    float4 c = *(const float4*)(p + 8);
    r[0]=a.x; r[1]=a.y; r[2]=a.z;  r[3]=a.w;
    r[4]=b.x; r[5]=b.y; r[6]=b.z;  r[7]=b.w;
    r[8]=c.x; r[9]=c.y; r[10]=c.z; r[11]=c.w;
}

__device__ __forceinline__ void conv_body(const float* __restrict__ inp,
                                          const float* __restrict__ wv, float* acc) {
    float rb[3][12];
    load_row(inp, rb[0]);
    load_row(inp + 12, rb[1]);
#pragma unroll
    for (int oy = 0; oy < 9; oy++) {
        load_row(inp + (oy + 2) * 12, rb[(oy + 2) % 3]);
#pragma unroll
        for (int ky = 0; ky < 3; ky++) {
            const float* r = rb[(oy + ky) % 3];
#pragma unroll
            for (int ox = 0; ox < 9; ox++) {
                float s = acc[oy * 9 + ox];
                s = fmaf(r[ox + 0], wv[ky * 3 + 0], s);
                s = fmaf(r[ox + 1], wv[ky * 3 + 1], s);
                s = fmaf(r[ox + 2], wv[ky * 3 + 2], s);
                acc[oy * 9 + ox] = s;
            }
        }
    }
}

__global__ __launch_bounds__(128) void conv1_kernel(const float* __restrict__ xin,
        const float* __restrict__ wt, const float* __restrict__ bias,
        bf16* __restrict__ xout, float* __restrict__ sacc) {
    __shared__ __align__(16) float lds[4 * 3 * 132];
    __shared__ float Sl[128], Ql[128];
    int t = threadIdx.x;
    int img0 = blockIdx.x * 4;
    for (int i = t; i < 4 * 3 * 132; i += 128) lds[i] = 0.f;
    __syncthreads();
    const float* src = xin + (size_t)img0 * 243;
    for (int i = t; i < 4 * 243; i += 128) {
        int il = i / 243, rem = i - il * 243;
        int ci = rem / 81, px = rem - ci * 81;
        lds[(il * 3 + ci) * 132 + (px / 9 + 1) * 12 + (px % 9) + 1] = src[i];
    }
    __syncthreads();
    int oc = t & 31, il = t >> 5;
    const float* base = lds + il * 3 * 132;
    float acc[81];
    float bb = bias[oc];
#pragma unroll
    for (int i = 0; i < 81; i++) acc[i] = bb;
#pragma unroll
    for (int ci = 0; ci < 3; ci++) {
        float wv[9];
#pragma unroll
        for (int k = 0; k < 9; k++) wv[k] = wt[(ci * 9 + k) * 32 + oc];
        conv_body(base + ci * 132, wv, acc);
    }
    bf16* dst = xout + (size_t)(img0 + il) * 81 * 32 + oc;
    float s = 0.f, q = 0.f;
#pragma unroll
    for (int p = 0; p < 81; p++) {
        float v = acc[p];
        s += v; q = fmaf(v, v, q);
        dst[p * 32] = __float2bfloat16(v);
    }
    Sl[il * 32 + oc] = s;
    Ql[il * 32 + oc] = q;
    __syncthreads();
    if (t < 32)
        atomicAdd(&sacc[t], Sl[t] + Sl[32 + t] + Sl[64 + t] + Sl[96 + t]);
    else if (t < 64) {
        int c = t - 32;
        atomicAdd(&sacc[32 + c], Ql[c] + Ql[32 + c] + Ql[64 + c] + Ql[96 + c]);
    }
}

// ------- LDS-staged MFMA conv, inline BN on A, fused out-stats -------------
// xin: RAW pre-BN bf16 [img][81][CI]; st: fused scale/shift for input layer;
// wm: bf16 [oc][9tap][CI]; out RAW pre-BN bf16 [img][81][COT].
template <int CI, int COT, int OCS>
__global__ __launch_bounds__(256, 2) void conv_tile(const bf16* __restrict__ xin,
        const bf16* __restrict__ wm, const float* __restrict__ bias,
        const float* __restrict__ st, bf16* __restrict__ xout,
        float* __restrict__ sacc) {
    constexpr int NCH = CI / 32;
    constexpr int ROW = 9 * CI;
    constexpr int STEPS = 9 * NCH;
    constexpr int PHASES = STEPS / 9;      // conv2: 1, conv3: 2
    constexpr int HS = STEPS / PHASES;     // 9 steps per phase
    __shared__ bf16 Bs[HS * 4 * 64 * 8];
    __shared__ float Ss[2][4][64];

    const int lin = blockIdx.x;
    const int xcd = lin & 7;
    const int slot = lin >> 3;
    constexpr int PSL = 81 * OCS;
    const int igl = slot / PSL;
    const int rem = slot - igl * PSL;
    const int p = rem / OCS;
    const int ob = rem - p * OCS;
    const int ig = xcd * 4 + igl;          // 32 groups of 256 imgs
    const int oc0 = ob * 64;
    const int py = p / 9, pxx = p - py * 9;
    const int tid = threadIdx.x;
    const int lane = tid & 63, wv = tid >> 6;
    const int m = lane & 15, quad = lane >> 4;
    const long img0 = (long)ig * 256 + wv * 64;

    int qt[9]; bool vt[9];
#pragma unroll
    for (int t = 0; t < 9; t++) {
        int iy = py + t / 3 - 1, ix = pxx + (t % 3) - 1;
        vt[t] = ((unsigned)iy < 9u) && ((unsigned)ix < 9u);
        qt[t] = vt[t] ? iy * 9 + ix : p;   // clamped safe address
    }

    // per-lane BN constants for this layer's input channels
    float scv[NCH][8], shv[NCH][8];
#pragma unroll
    for (int ch = 0; ch < NCH; ch++)
#pragma unroll
        for (int j = 0; j < 8; j++) {
            int ci = ch * 32 + quad * 8 + j;
            scv[ch][j] = st[ci];
            shv[ch][j] = st[CI + ci];
        }

    f32x4 acc[4][4];
#pragma unroll
    for (int nf = 0; nf < 4; nf++) {
        float bb = bias[oc0 + nf * 16 + m];
#pragma unroll
        for (int ms = 0; ms < 4; ms++) {
            acc[ms][nf][0] = bb; acc[ms][nf][1] = bb;
            acc[ms][nf][2] = bb; acc[ms][nf][3] = bb;
        }
    }
    const bf16* ab[4];
#pragma unroll
    for (int ms = 0; ms < 4; ms++)
        ab[ms] = xin + (img0 + ms * 16 + m) * (81 * CI) + quad * 8;

    const bf16* bsl = &Bs[lane * 8];
    const bf16x8 zf = {0, 0, 0, 0, 0, 0, 0, 0};

#pragma unroll
    for (int ph = 0; ph < PHASES; ph++) {
        __syncthreads();
        for (int i = tid; i < HS * 4 * 64; i += 256) {
            int l2 = i & 63, nf = (i >> 6) & 3, sl = i >> 8;
            int s = ph * HS + sl;
            int t = s / NCH, ch = s - t * NCH;
            int mm = l2 & 15, qq = l2 >> 4;
            *(bf16x8*)(&Bs[(size_t)i * 8]) =
                *(const bf16x8*)(wm + (size_t)(oc0 + nf * 16 + mm) * ROW + t * CI + ch * 32 + qq * 8);
        }
        __syncthreads();
#pragma unroll
        for (int sl = 0; sl < HS; sl++) {
            const int s = ph * HS + sl;
            const int t = s / NCH, ch = s - t * NCH;
            bf16x8 bfr[4];
#pragma unroll
            for (int nf = 0; nf < 4; nf++)
                bfr[nf] = *(const bf16x8*)(bsl + (sl * 4 + nf) * 512);
            bf16x8 a[4];
#pragma unroll
            for (int ms = 0; ms < 4; ms++)
                a[ms] = *(const bf16x8*)(ab[ms] + qt[t] * CI + ch * 32);
#pragma unroll
            for (int ms = 0; ms < 4; ms++) {
                bf16x8 v = vt[t] ? bn8(a[ms], scv[ch], shv[ch]) : zf;
#pragma unroll
                for (int nf = 0; nf < 4; nf++)
                    acc[ms][nf] = __builtin_amdgcn_mfma_f32_16x16x32_bf16(v, bfr[nf], acc[ms][nf], 0, 0, 0);
            }
        }
    }

    // stores: D col = lane&15 (oc), row = quad*4 + reg (img)
    bf16* orow = xout + (img0 + quad * 4) * (81 * COT) + (size_t)p * COT + oc0 + m;
#pragma unroll
    for (int ms = 0; ms < 4; ms++)
#pragma unroll
        for (int nf = 0; nf < 4; nf++)
#pragma unroll
            for (int r = 0; r < 4; r++)
                orow[(size_t)(ms * 16 + r) * (81 * COT) + nf * 16] =
                    __float2bfloat16(acc[ms][nf][r]);

    // fused BN stats: per-oc sum / sumsq over this block's outputs
    float ssum[4], sq[4];
#pragma unroll
    for (int nf = 0; nf < 4; nf++) {
        float s = 0.f, q = 0.f;
#pragma unroll
        for (int ms = 0; ms < 4; ms++)
#pragma unroll
            for (int r = 0; r < 4; r++) {
                float v = acc[ms][nf][r];
                s += v; q = fmaf(v, v, q);
            }
        s += __shfl_xor(s, 16); s += __shfl_xor(s, 32);
        q += __shfl_xor(q, 16); q += __shfl_xor(q, 32);
        ssum[nf] = s; sq[nf] = q;
    }
    if (lane < 16) {
#pragma unroll
        for (int nf = 0; nf < 4; nf++) {
            Ss[0][wv][nf * 16 + lane] = ssum[nf];
            Ss[1][wv][nf * 16 + lane] = sq[nf];
        }
    }
    __syncthreads();
    if (tid < 64) {
        float a = Ss[0][0][tid] + Ss[0][1][tid] + Ss[0][2][tid] + Ss[0][3][tid];
        atomicAdd(&sacc[oc0 + tid], a);
    } else if (tid < 128) {
        int c = tid - 64;
        float a = Ss[1][0][c] + Ss[1][1][c] + Ss[1][2][c] + Ss[1][3][c];
        atomicAdd(&sacc[COT + oc0 + c], a);
    }
}

// ---------------- encoder: raw x3 + inline BN3; M=8192, N=128, K=10368 -----
// Grid 512: xcd = lin&7 owns igl(8, 128-img groups) x {ks(4) x nh(2)}.
__global__ __launch_bounds__(256) void enc_mfma(const bf16* __restrict__ x3,
        const bf16* __restrict__ ewb, const float* __restrict__ st,
        float* __restrict__ part) {
    const int lin = blockIdx.x;
    const int xcd = lin & 7;
    const int slot = lin >> 3;           // 0..63
    const int igl = slot >> 3;           // 0..7
    const int combo = slot & 7;
    const int ks = combo >> 1, nh = combo & 1;
    const int ig = xcd * 8 + igl;        // 64 groups of 128 imgs
    const int lane = threadIdx.x & 63, wv = threadIdx.x >> 6;
    const int m = lane & 15, quad = lane >> 4;
    const long img0 = (long)ig * 128 + wv * 32;

    // BN3 per-lane constants; chunk c's ci base = 32*((ks+c)&3) + quad*8
    float scv[4][8], shv[4][8];
#pragma unroll
    for (int cc = 0; cc < 4; cc++)
#pragma unroll
        for (int j = 0; j < 8; j++) {
            int ci = cc * 32 + quad * 8 + j;
            scv[cc][j] = st[ci];
            shv[cc][j] = st[128 + ci];
        }

    f32x4 acc[2][4];
#pragma unroll
    for (int ms = 0; ms < 2; ms++)
#pragma unroll
        for (int nf = 0; nf < 4; nf++) {
            acc[ms][nf][0]=0.f; acc[ms][nf][1]=0.f; acc[ms][nf][2]=0.f; acc[ms][nf][3]=0.f;
        }
    const bf16* ab[2];
    const bf16* bb[4];
#pragma unroll
    for (int ms = 0; ms < 2; ms++)
        ab[ms] = x3 + (img0 + ms * 16 + m) * FLAT + ks * 2592 + quad * 8;
#pragma unroll
    for (int nf = 0; nf < 4; nf++)
        bb[nf] = ewb + (size_t)(nh * 64 + nf * 16 + m) * FLAT + ks * 2592 + quad * 8;

#pragma unroll 3
    for (int c = 0; c < 81; c++) {
        const int cc = (ks + c) & 3;
        bf16x8 Ac[2], Bc[4];
#pragma unroll
        for (int ms = 0; ms < 2; ms++) {
            bf16x8 raw = *(const bf16x8*)(ab[ms] + c * 32);
            Ac[ms] = bn8(raw, scv[cc], shv[cc]);
        }
#pragma unroll
        for (int nf = 0; nf < 4; nf++) Bc[nf] = *(const bf16x8*)(bb[nf] + c * 32);
#pragma unroll
        for (int nf = 0; nf < 4; nf++)
#pragma unroll
            for (int ms = 0; ms < 2; ms++)
                acc[ms][nf] = __builtin_amdgcn_mfma_f32_16x16x32_bf16(Ac[ms], Bc[nf], acc[ms][nf], 0, 0, 0);
    }

    float* pp = part + (size_t)ks * (NIMG * 128) + (img0 + quad * 4) * 128 + nh * 64 + m;
#pragma unroll
    for (int ms = 0; ms < 2; ms++)
#pragma unroll
        for (int nf = 0; nf < 4; nf++)
#pragma unroll
            for (int r = 0; r < 4; r++)
                pp[(ms * 16 + r) * 128 + nf * 16] = acc[ms][nf][r];
}

template <int CO>
__global__ void stats_fin(const float* __restrict__ acc, const float* __restrict__ gamma,
                          const float* __restrict__ beta, float* __restrict__ st) {
    int c = threadIdx.x;
    if (c < CO) {
        const float inv = 1.0f / (8192.0f * 81.0f);
        float m = acc[c] * inv;
        float var = acc[CO + c] * inv - m * m;
        float istd = rsqrtf(var + 1e-5f);
        float sc = istd * gamma[c];
        st[c] = sc;
        st[CO + c] = beta[c] - m * sc;
    }
}

// ---- k-split reduce + bias + transpose: xT[b][f][n] = sum parts + encb ----
__global__ void enc_reduce(const float* __restrict__ part, const float* __restrict__ encb,
                           float* __restrict__ xT) {
    int i = blockIdx.x * 256 + threadIdx.x;
    const int NP = NIMG * 128;
    if (i < NP) {
        float v = part[i] + part[NP + i] + part[2 * NP + i] + part[3 * NP + i] + encb[i & 127];
        int img = i >> 7, f = i & 127;
        xT[(size_t)(img >> 7) * 16384 + f * 128 + (img & 127)] = v;
    }
}

// Y[b] = A[b] (128x128) @ S[b] (128x128)
__global__ __launch_bounds__(256) void mm_xs(const float* __restrict__ A,
        const float* __restrict__ S, float* __restrict__ Y) {
    __shared__ __align__(16) float Sc[32 * 132];
    __shared__ float Acm[32 * 33];
    int b = blockIdx.y, f0 = blockIdx.x * 32;
    int t = threadIdx.x;
    int fl = t & 31, mg = t >> 5;
    const float* Ab = A + (size_t)b * 16384;
    const float* Sb = S + (size_t)b * 16384;
    float acc[16];
#pragma unroll
    for (int j = 0; j < 16; j++) acc[j] = 0.f;
    for (int nc = 0; nc < 128; nc += 32) {
#pragma unroll
        for (int r = 0; r < 4; r++) {
            int i4 = r * 256 + t;
            int nn = i4 >> 5, m4 = (i4 & 31) * 4;
            *(float4*)&Sc[nn * 132 + m4] = *(const float4*)&Sb[(size_t)(nc + nn) * 128 + m4];
        }
#pragma unroll
        for (int r = 0; r < 4; r++) {
            int i = r * 256 + t;
            int ff = i >> 5, nn = i & 31;
            Acm[ff * 33 + nn] = Ab[(size_t)(f0 + ff) * 128 + nc + nn];
        }
        __syncthreads();
#pragma unroll 4
        for (int nn = 0; nn < 32; nn++) {
            float a = Acm[fl * 33 + nn];
#pragma unroll
            for (int j = 0; j < 4; j++) {
                float4 s4 = *(const float4*)&Sc[nn * 132 + mg * 16 + j * 4];
                acc[j*4+0] = fmaf(a, s4.x, acc[j*4+0]);
                acc[j*4+1] = fmaf(a, s4.y, acc[j*4+1]);
                acc[j*4+2] = fmaf(a, s4.z, acc[j*4+2]);
                acc[j*4+3] = fmaf(a, s4.w, acc[j*4+3]);
            }
        }
        __syncthreads();
    }
    float* yb = Y + (size_t)b * 16384 + (size_t)(f0 + fl) * 128 + mg * 16;
#pragma unroll
    for (int j = 0; j < 4; j++)
        *(float4*)&yb[j * 4] = make_float4(acc[j*4], acc[j*4+1], acc[j*4+2], acc[j*4+3]);
}

// Out[b][g][n] = relu( sum_f W0[g,f]Z0 + W1 Z1 + W2 Z2 + bias[g] )
__global__ __launch_bounds__(256) void gf_combine(const float* __restrict__ Z0,
        const float* __restrict__ Z1, const float* __restrict__ Z2,
        const float* __restrict__ W, const float* __restrict__ bias,
        float* __restrict__ out) {
    __shared__ __align__(16) float Zc[32 * 132];
    __shared__ float Wc[32 * 33];
    int b = blockIdx.y, g0 = blockIdx.x * 32;
    int t = threadIdx.x;
    int gl = t & 31, mg = t >> 5;
    float acc[16];
    float bb = bias[g0 + gl];
#pragma unroll
    for (int j = 0; j < 16; j++) acc[j] = bb;
    const float* Zs[3] = {Z0 + (size_t)b * 16384, Z1 + (size_t)b * 16384, Z2 + (size_t)b * 16384};
    for (int j3 = 0; j3 < 3; j3++) {
        const float* Zb = Zs[j3];
        const float* Wj = W + j3 * 16384;
        for (int fc = 0; fc < 128; fc += 32) {
#pragma unroll
            for (int r = 0; r < 4; r++) {
                int i4 = r * 256 + t;
                int ff = i4 >> 5, m4 = (i4 & 31) * 4;
                *(float4*)&Zc[ff * 132 + m4] = *(const float4*)&Zb[(size_t)(fc + ff) * 128 + m4];
            }
#pragma unroll
            for (int r = 0; r < 4; r++) {
                int i = r * 256 + t;
                int gg = i >> 5, ff = i & 31;
                Wc[gg * 33 + ff] = Wj[(size_t)(g0 + gg) * 128 + fc + ff];
            }
            __syncthreads();
#pragma unroll 4
            for (int ff = 0; ff < 32; ff++) {
                float w = Wc[gl * 33 + ff];
#pragma unroll
                for (int j = 0; j < 4; j++) {
                    float4 z4 = *(const float4*)&Zc[ff * 132 + mg * 16 + j * 4];
                    acc[j*4+0] = fmaf(w, z4.x, acc[j*4+0]);
                    acc[j*4+1] = fmaf(w, z4.y, acc[j*4+1]);
                    acc[j*4+2] = fmaf(w, z4.z, acc[j*4+2]);
                    acc[j*4+3] = fmaf(w, z4.w, acc[j*4+3]);
                }
            }
            __syncthreads();
        }
    }
    float* ob = out + (size_t)b * 16384 + (size_t)(g0 + gl) * 128 + mg * 16;
#pragma unroll
    for (int j = 0; j < 4; j++)
        *(float4*)&ob[j * 4] = make_float4(fmaxf(acc[j*4], 0.f), fmaxf(acc[j*4+1], 0.f),
                                           fmaxf(acc[j*4+2], 0.f), fmaxf(acc[j*4+3], 0.f));
}

// logits[b,n,a] = sum_g X[b][g][n] * aw[a][g] + ab[a]
__global__ __launch_bounds__(128) void act_kernel(const float* __restrict__ X,
        const float* __restrict__ aw, const float* __restrict__ ab,
        float* __restrict__ out) {
    int b = blockIdx.x, n = threadIdx.x;
    float acc[5];
#pragma unroll
    for (int a = 0; a < 5; a++) acc[a] = ab[a];
    const float* xb = X + (size_t)b * 16384 + n;
#pragma unroll 4
    for (int g = 0; g < 128; g++) {
        float v = xb[(size_t)g * 128];
#pragma unroll
        for (int a = 0; a < 5; a++) acc[a] = fmaf(v, aw[a * 128 + g], acc[a]);
    }
    float* ob = out + ((size_t)b * 128 + n) * 5;
#pragma unroll
    for (int a = 0; a < 5; a++) ob[a] = acc[a];
}

// ---------------------------------------------------------------------------
extern "C" void kernel_launch(void* const* d_in, const int* in_sizes, int n_in,
                              void* d_out, int out_size, void* d_ws, size_t ws_size,
                              hipStream_t stream) {
    const float* states = (const float*)d_in[0];
    const float* gso    = (const float*)d_in[1];
    const float* c1w  = (const float*)d_in[2];
    const float* c1b  = (const float*)d_in[3];
    const float* c1g  = (const float*)d_in[4];
    const float* c1be = (const float*)d_in[5];
    const float* c2w  = (const float*)d_in[6];
    const float* c2b  = (const float*)d_in[7];
    const float* c2g  = (const float*)d_in[8];
    const float* c2be = (const float*)d_in[9];
    const float* c3w  = (const float*)d_in[10];
    const float* c3b  = (const float*)d_in[11];
    const float* c3g  = (const float*)d_in[12];
    const float* c3be = (const float*)d_in[13];
    const float* encw = (const float*)d_in[14];
    const float* encb = (const float*)d_in[15];
    const float* g1w  = (const float*)d_in[16];
    const float* g1b  = (const float*)d_in[17];
    const float* g2w  = (const float*)d_in[18];
    const float* g2b  = (const float*)d_in[19];
    const float* aw   = (const float*)d_in[20];
    const float* ab   = (const float*)d_in[21];
    float* out = (float*)d_out;
    char* ws = (char*)d_ws;

    size_t o = 0;
    auto take = [&](size_t bytes) { size_t r = o; o += (bytes + 255) & ~(size_t)255; return r; };
    const size_t o_x3  = take((size_t)NIMG * 81 * 128 * 2);   // 169,869,312
    const size_t o_x2  = take((size_t)NIMG * 81 * 64 * 2);    //  84,934,656
    const size_t o_w1t = take(27 * 32 * 4);
    const size_t o_w2m = take(64 * 288 * 2);
    const size_t o_w3m = take(128 * 576 * 2);
    const size_t o_acc = take(448 * 4);
    const size_t o_st1 = take(2 * 32 * 4);
    const size_t o_st2 = take(2 * 64 * 4);
    const size_t o_st3 = take(2 * 128 * 4);
    if (ws_size < o) {
        fill_sentinel<<<(out_size + 255) / 256, 256, 0, stream>>>(out, out_size);
        return;
    }

    const size_t o_x1 = o_x3;                       // x1 at head of x3 region
    const size_t o_ewb  = o_x2;                     // 2,654,208 (aliases dead x2)
    const size_t o_part = o_x2 + 2654208;           // 16,777,216 (4 k-split partials)
    const size_t o_xT   = o_part + 16777216;
    const size_t o_y1   = o_xT + 4194304;
    const size_t o_y2   = o_y1 + 4194304;
    const size_t o_G1   = o_y2 + 4194304;
    const size_t o_G2   = o_G1 + 4194304;           // ends ~40MB < 85MB region

    bf16* x1 = (bf16*)(ws + o_x1);
    bf16* x2 = (bf16*)(ws + o_x2);
    bf16* x3 = (bf16*)(ws + o_x3);
    float* w1t = (float*)(ws + o_w1t);
    bf16* w2m = (bf16*)(ws + o_w2m);
    bf16* w3m = (bf16*)(ws + o_w3m);
    float* acc1 = (float*)(ws + o_acc);
    float* acc2 = acc1 + 64;
    float* acc3 = acc1 + 192;
    float* st1 = (float*)(ws + o_st1);
    float* st2 = (float*)(ws + o_st2);
    float* st3 = (float*)(ws + o_st3);
    bf16* ewb = (bf16*)(ws + o_ewb);
    float* partp = (float*)(ws + o_part);
    float* xT = (float*)(ws + o_xT);
    float* y1 = (float*)(ws + o_y1);
    float* y2 = (float*)(ws + o_y2);
    float* xG1 = (float*)(ws + o_G1);
    float* xG2 = (float*)(ws + o_G2);

    hipMemsetAsync(ws + o_acc, 0, 448 * 4, stream);
    prep_w<<<128, 256, 0, stream>>>(c1w, c2w, c3w, w1t, w2m, w3m);

    conv1_kernel<<<2048, 128, 0, stream>>>(states, w1t, c1b, x1, acc1);
    stats_fin<32><<<1, 32, 0, stream>>>(acc1, c1g, c1be, st1);

    conv_tile<32, 64, 1><<<2592, 256, 0, stream>>>(x1, w2m, c2b, st1, x2, acc2);
    stats_fin<64><<<1, 64, 0, stream>>>(acc2, c2g, c2be, st2);

    conv_tile<64, 128, 2><<<5184, 256, 0, stream>>>(x2, w3m, c3b, st2, x3, acc3);
    stats_fin<128><<<1, 128, 0, stream>>>(acc3, c3g, c3be, st3);

    prep_enc<<<2048, 256, 0, stream>>>(encw, ewb);
    enc_mfma<<<512, 256, 0, stream>>>(x3, ewb, st3, partp);
    enc_reduce<<<4096, 256, 0, stream>>>(partp, encb, xT);

    mm_xs<<<dim3(4, 64), 256, 0, stream>>>(xT, gso, y1);
    mm_xs<<<dim3(4, 64), 256, 0, stream>>>(y1, gso, y2);
    gf_combine<<<dim3(4, 64), 256, 0, stream>>>(xT, y1, y2, g1w, g1b, xG1);

    mm_xs<<<dim3(4, 64), 256, 0, stream>>>(xG1, gso, y1);
    mm_xs<<<dim3(4, 64), 256, 0, stream>>>(y1, gso, y2);
    gf_combine<<<dim3(4, 64), 256, 0, stream>>>(xG1, y1, y2, g2w, g2b, xG2);

    act_kernel<<<64, 128, 0, stream>>>(xG2, aw, ab, out);
}

// Round 15
// 752.858 us; speedup vs baseline: 1.1691x; 1.0585x over previous
//
#include <hip/hip_runtime.h>
#include <hip/hip_bf16.h>
#include <stdint.h>

// ---------------------------------------------------------------------------
// Network_60163901882451 — round 15: K-group-contiguous activations.
// Layout [px][ch][img][32] (ch = ci/32): one MFMA A-frag = 64 lanes x 16B
// consecutive = ONE contiguous 1KB wave access (r13's [px][img][ci] was still
// stride-2 at CI=64 -> 16 disjoint segments/load saturating the CU's TA).
// Rest identical to r14: inline BN on consumer A-paths, fused out-stats,
// 2-phase fragment-ordered LDS weights, transpose folded into enc_reduce.
// ---------------------------------------------------------------------------

#define NIMG 8192
#define NPIX 81
#define FLAT 10368

typedef __hip_bfloat16 bf16;
typedef short bf16x8 __attribute__((ext_vector_type(8)));
typedef float f32x4 __attribute__((ext_vector_type(4)));

__device__ __forceinline__ float bflo(unsigned u) { return __uint_as_float(u << 16); }
__device__ __forceinline__ float bfhi(unsigned u) { return __uint_as_float(u & 0xffff0000u); }
__device__ __forceinline__ unsigned short f2bf(float f) {
    unsigned u = __float_as_uint(f);
    return (unsigned short)((u + 0x7fff + ((u >> 16) & 1)) >> 16);
}

// BN+relu on a bf16x8 fragment; sc/sh are per-element (ci-indexed) registers
__device__ __forceinline__ bf16x8 bn8(bf16x8 a, const float* sc, const float* sh) {
    union U { bf16x8 v; unsigned u[4]; } in, out;
    in.v = a;
#pragma unroll
    for (int d = 0; d < 4; d++) {
        float lo = fmaxf(fmaf(bflo(in.u[d]), sc[2 * d],     sh[2 * d]),     0.f);
        float hi = fmaxf(fmaf(bfhi(in.u[d]), sc[2 * d + 1], sh[2 * d + 1]), 0.f);
        out.u[d] = (unsigned)f2bf(lo) | ((unsigned)f2bf(hi) << 16);
    }
    return out.v;
}

__global__ void fill_sentinel(float* __restrict__ out, int n) {
    int i = blockIdx.x * 256 + threadIdx.x;
    if (i < n) out[i] = 1.0e9f;   // ws_size-too-small signature
}

// ---------------- weight preps ---------------------------------------------
__global__ void prep_w(const float* __restrict__ c1w, const float* __restrict__ c2w,
                       const float* __restrict__ c3w,
                       float* __restrict__ w1t, bf16* __restrict__ w2m,
                       bf16* __restrict__ w3m) {
    int i0 = blockIdx.x * blockDim.x + threadIdx.x;
    int stride = gridDim.x * blockDim.x;
    for (int i = i0; i < 27 * 32; i += stride) w1t[i] = c1w[(i & 31) * 27 + (i >> 5)];
    for (int i = i0; i < 64 * 288; i += stride) {
        int oc = i / 288, r = i - oc * 288, t = r >> 5, ci = r & 31;
        w2m[i] = __float2bfloat16(c2w[oc * 288 + ci * 9 + t]);
    }
    for (int i = i0; i < 128 * 576; i += stride) {
        int oc = i / 576, r = i - oc * 576, t = r >> 6, ci = r & 63;
        w3m[i] = __float2bfloat16(c3w[oc * 576 + ci * 9 + t]);
    }
}

// ewb[e][(px*4+cc)*32+c32] = encw[e][(cc*32+c32)*81+px]  (K-chunk order)
__global__ void prep_enc(const float* __restrict__ encw, bf16* __restrict__ ewb) {
    int i0 = blockIdx.x * blockDim.x + threadIdx.x;
    int stride = gridDim.x * blockDim.x;
    for (int i = i0; i < 128 * FLAT; i += stride) {
        int e = i / FLAT, r = i - e * FLAT;
        int kk = r >> 5, c32 = r & 31;
        int px = kk >> 2, cc = kk & 3;
        ewb[i] = __float2bfloat16(encw[(size_t)e * FLAT + (cc * 32 + c32) * 81 + px]);
    }
}

// ---------------- conv1 (direct fp32; fused stats; [px][img][32] out) ------
__device__ __forceinline__ void load_row(const float* __restrict__ p, float* r) {
    float4 a = *(const float4*)p;
    float4 b = *(const float4*)(p + 4);
    float4 c = *(const float4*)(p + 8);
    r[0]=a.x; r[1]=a.y; r[2]=a.z;  r[3]=a.w;
    r[4]=b.x; r[5]=b.y; r[6]=b.z;  r[7]=b.w;
    r[8]=c.x; r[9]=c.y; r[10]=c.z; r[11]=c.w;
}

__device__ __forceinline__ void conv_body(const float* __restrict__ inp,
                                          const float* __restrict__ wv, float* acc) {
    float rb[3][12];
    load_row(inp, rb[0]);
    load_row(inp + 12, rb[1]);
#pragma unroll
    for (int oy = 0; oy < 9; oy++) {
        load_row(inp + (oy + 2) * 12, rb[(oy + 2) % 3]);
#pragma unroll
        for (int ky = 0; ky < 3; ky++) {
            const float* r = rb[(oy + ky) % 3];
#pragma unroll
            for (int ox = 0; ox < 9; ox++) {
                float s = acc[oy * 9 + ox];
                s = fmaf(r[ox + 0], wv[ky * 3 + 0], s);
                s = fmaf(r[ox + 1], wv[ky * 3 + 1], s);
                s = fmaf(r[ox + 2], wv[ky * 3 + 2], s);
                acc[oy * 9 + ox] = s;
            }
        }
    }
}

__global__ __launch_bounds__(128) void conv1_kernel(const float* __restrict__ xin,
        const float* __restrict__ wt, const float* __restrict__ bias,
        bf16* __restrict__ xout, float* __restrict__ sacc) {
    __shared__ __align__(16) float lds[4 * 3 * 132];
    __shared__ float Sl[128], Ql[128];
    int t = threadIdx.x;
    int img0 = blockIdx.x * 4;
    for (int i = t; i < 4 * 3 * 132; i += 128) lds[i] = 0.f;
    __syncthreads();
    const float* src = xin + (size_t)img0 * 243;
    for (int i = t; i < 4 * 243; i += 128) {
        int il = i / 243, rem = i - il * 243;
        int ci = rem / 81, px = rem - ci * 81;
        lds[(il * 3 + ci) * 132 + (px / 9 + 1) * 12 + (px % 9) + 1] = src[i];
    }
    __syncthreads();
    int oc = t & 31, il = t >> 5;
    const float* base = lds + il * 3 * 132;
    float acc[81];
    float bb = bias[oc];
#pragma unroll
    for (int i = 0; i < 81; i++) acc[i] = bb;
#pragma unroll
    for (int ci = 0; ci < 3; ci++) {
        float wv[9];
#pragma unroll
        for (int k = 0; k < 9; k++) wv[k] = wt[(ci * 9 + k) * 32 + oc];
        conv_body(base + ci * 132, wv, acc);
    }
    // out: [px][img][32]
    bf16* dst = xout + (size_t)(img0 + il) * 32 + oc;
    const size_t PXS = (size_t)NIMG * 32;
    float s = 0.f, q = 0.f;
#pragma unroll
    for (int p = 0; p < 81; p++) {
        float v = acc[p];
        s += v; q = fmaf(v, v, q);
        dst[p * PXS] = __float2bfloat16(v);
    }
    Sl[il * 32 + oc] = s;
    Ql[il * 32 + oc] = q;
    __syncthreads();
    if (t < 32)
        atomicAdd(&sacc[t], Sl[t] + Sl[32 + t] + Sl[64 + t] + Sl[96 + t]);
    else if (t < 64) {
        int c = t - 32;
        atomicAdd(&sacc[32 + c], Ql[c] + Ql[32 + c] + Ql[64 + c] + Ql[96 + c]);
    }
}

// ------- LDS-staged MFMA conv, inline BN on A, fused out-stats -------------
// xin: RAW bf16 [81][NCH][NIMG][32]; wm: bf16 [oc][9tap][CI];
// out RAW bf16 [81][NCHO][NIMG][32]. Block: 256 imgs x 64 oc x 1 pixel.
template <int CI, int COT, int OCS>
__global__ __launch_bounds__(256, 2) void conv_tile(const bf16* __restrict__ xin,
        const bf16* __restrict__ wm, const float* __restrict__ bias,
        const float* __restrict__ st, bf16* __restrict__ xout,
        float* __restrict__ sacc) {
    constexpr int NCH = CI / 32;
    constexpr int NCHO = COT / 32;
    constexpr int ROW = 9 * CI;
    constexpr int STEPS = 9 * NCH;
    constexpr int PHASES = STEPS / 9;      // conv2: 1, conv3: 2
    constexpr int HS = STEPS / PHASES;     // 9 steps per phase
    constexpr size_t CSTRIDE = (size_t)NIMG * 32;   // one (px,ch) slot
    __shared__ bf16 Bs[HS * 4 * 64 * 8];
    __shared__ float Ss[2][4][64];

    const int lin = blockIdx.x;
    const int xcd = lin & 7;
    const int slot = lin >> 3;
    constexpr int PSL = 81 * OCS;
    const int igl = slot / PSL;
    const int rem = slot - igl * PSL;
    const int p = rem / OCS;
    const int ob = rem - p * OCS;
    const int ig = xcd * 4 + igl;          // 32 groups of 256 imgs
    const int oc0 = ob * 64;
    const int py = p / 9, pxx = p - py * 9;
    const int tid = threadIdx.x;
    const int lane = tid & 63, wv = tid >> 6;
    const int m = lane & 15, quad = lane >> 4;
    const long img0 = (long)ig * 256 + wv * 64;

    int qt[9]; bool vt[9];
#pragma unroll
    for (int t = 0; t < 9; t++) {
        int iy = py + t / 3 - 1, ix = pxx + (t % 3) - 1;
        vt[t] = ((unsigned)iy < 9u) && ((unsigned)ix < 9u);
        qt[t] = vt[t] ? iy * 9 + ix : p;   // clamped safe address
    }

    // per-lane BN constants for this layer's input channels
    float scv[NCH][8], shv[NCH][8];
#pragma unroll
    for (int ch = 0; ch < NCH; ch++)
#pragma unroll
        for (int j = 0; j < 8; j++) {
            int ci = ch * 32 + quad * 8 + j;
            scv[ch][j] = st[ci];
            shv[ch][j] = st[CI + ci];
        }

    f32x4 acc[4][4];
#pragma unroll
    for (int nf = 0; nf < 4; nf++) {
        float bb = bias[oc0 + nf * 16 + m];
#pragma unroll
        for (int ms = 0; ms < 4; ms++) {
            acc[ms][nf][0] = bb; acc[ms][nf][1] = bb;
            acc[ms][nf][2] = bb; acc[ms][nf][3] = bb;
        }
    }
    // A base: [px][ch][img][32] -> frag = contiguous 1KB per wave
    const bf16* ab[4];
#pragma unroll
    for (int ms = 0; ms < 4; ms++)
        ab[ms] = xin + (img0 + ms * 16 + m) * 32 + quad * 8;

    const bf16* bsl = &Bs[lane * 8];
    const bf16x8 zf = {0, 0, 0, 0, 0, 0, 0, 0};

#pragma unroll
    for (int ph = 0; ph < PHASES; ph++) {
        __syncthreads();
        for (int i = tid; i < HS * 4 * 64; i += 256) {
            int l2 = i & 63, nf = (i >> 6) & 3, sl = i >> 8;
            int s = ph * HS + sl;
            int t = s / NCH, ch = s - t * NCH;
            int mm = l2 & 15, qq = l2 >> 4;
            *(bf16x8*)(&Bs[(size_t)i * 8]) =
                *(const bf16x8*)(wm + (size_t)(oc0 + nf * 16 + mm) * ROW + t * CI + ch * 32 + qq * 8);
        }
        __syncthreads();
#pragma unroll
        for (int sl = 0; sl < HS; sl++) {
            const int s = ph * HS + sl;
            const int t = s / NCH, ch = s - t * NCH;
            bf16x8 bfr[4];
#pragma unroll
            for (int nf = 0; nf < 4; nf++)
                bfr[nf] = *(const bf16x8*)(bsl + (sl * 4 + nf) * 512);
            bf16x8 a[4];
#pragma unroll
            for (int ms = 0; ms < 4; ms++)
                a[ms] = *(const bf16x8*)(ab[ms] + (size_t)(qt[t] * NCH + ch) * CSTRIDE);
#pragma unroll
            for (int ms = 0; ms < 4; ms++) {
                bf16x8 v = vt[t] ? bn8(a[ms], scv[ch], shv[ch]) : zf;
#pragma unroll
                for (int nf = 0; nf < 4; nf++)
                    acc[ms][nf] = __builtin_amdgcn_mfma_f32_16x16x32_bf16(v, bfr[nf], acc[ms][nf], 0, 0, 0);
            }
        }
    }

    // stores: out[p][chO][img][32]; oc = oc0 + nf*16 + m -> chO = oc0/32+(nf>>1)
    const int och = oc0 >> 5;
#pragma unroll
    for (int ms = 0; ms < 4; ms++)
#pragma unroll
        for (int nf = 0; nf < 4; nf++) {
            bf16* orow = xout
                + (((size_t)p * NCHO + och + (nf >> 1)) * NIMG + img0 + ms * 16 + quad * 4) * 32
                + (nf & 1) * 16 + m;
#pragma unroll
            for (int r = 0; r < 4; r++)
                orow[r * 32] = __float2bfloat16(acc[ms][nf][r]);
        }

    // fused BN stats: per-oc sum / sumsq over this block's outputs
    float ssum[4], sq[4];
#pragma unroll
    for (int nf = 0; nf < 4; nf++) {
        float s = 0.f, q = 0.f;
#pragma unroll
        for (int ms = 0; ms < 4; ms++)
#pragma unroll
            for (int r = 0; r < 4; r++) {
                float v = acc[ms][nf][r];
                s += v; q = fmaf(v, v, q);
            }
        s += __shfl_xor(s, 16); s += __shfl_xor(s, 32);
        q += __shfl_xor(q, 16); q += __shfl_xor(q, 32);
        ssum[nf] = s; sq[nf] = q;
    }
    if (lane < 16) {
#pragma unroll
        for (int nf = 0; nf < 4; nf++) {
            Ss[0][wv][nf * 16 + lane] = ssum[nf];
            Ss[1][wv][nf * 16 + lane] = sq[nf];
        }
    }
    __syncthreads();
    if (tid < 64) {
        float a = Ss[0][0][tid] + Ss[0][1][tid] + Ss[0][2][tid] + Ss[0][3][tid];
        atomicAdd(&sacc[oc0 + tid], a);
    } else if (tid < 128) {
        int c = tid - 64;
        float a = Ss[1][0][c] + Ss[1][1][c] + Ss[1][2][c] + Ss[1][3][c];
        atomicAdd(&sacc[COT + oc0 + c], a);
    }
}

// ----- encoder: x3 = [81][4][NIMG][32] + inline BN3; K = 324 chunks of 32 --
// Grid 512: xcd = lin&7 owns igl(8, 128-img groups) x {ks(4) x nh(2)};
// ks takes K-chunks [ks*81, ks*81+81).
__global__ __launch_bounds__(256) void enc_mfma(const bf16* __restrict__ x3,
        const bf16* __restrict__ ewb, const float* __restrict__ st,
        float* __restrict__ part) {
    const int lin = blockIdx.x;
    const int xcd = lin & 7;
    const int slot = lin >> 3;           // 0..63
    const int igl = slot >> 3;           // 0..7
    const int combo = slot & 7;
    const int ks = combo >> 1, nh = combo & 1;
    const int ig = xcd * 8 + igl;        // 64 groups of 128 imgs
    const int lane = threadIdx.x & 63, wv = threadIdx.x >> 6;
    const int m = lane & 15, quad = lane >> 4;
    const long img0 = (long)ig * 128 + wv * 32;
    constexpr size_t CSTRIDE = (size_t)NIMG * 32;

    // BN3 per-lane constants; chunk index kk = ks*81+c -> cc = (ks+c)&3
    float scv[4][8], shv[4][8];
#pragma unroll
    for (int cc = 0; cc < 4; cc++)
#pragma unroll
        for (int j = 0; j < 8; j++) {
            int ci = cc * 32 + quad * 8 + j;
            scv[cc][j] = st[ci];
            shv[cc][j] = st[128 + ci];
        }

    f32x4 acc[2][4];
#pragma unroll
    for (int ms = 0; ms < 2; ms++)
#pragma unroll
        for (int nf = 0; nf < 4; nf++) {
            acc[ms][nf][0]=0.f; acc[ms][nf][1]=0.f; acc[ms][nf][2]=0.f; acc[ms][nf][3]=0.f;
        }
    const bf16* ab[2];
    const bf16* bb[4];
#pragma unroll
    for (int ms = 0; ms < 2; ms++)
        ab[ms] = x3 + (size_t)(ks * 81) * CSTRIDE + (img0 + ms * 16 + m) * 32 + quad * 8;
#pragma unroll
    for (int nf = 0; nf < 4; nf++)
        bb[nf] = ewb + (size_t)(nh * 64 + nf * 16 + m) * FLAT + ks * 81 * 32 + quad * 8;

#pragma unroll 3
    for (int c = 0; c < 81; c++) {
        const int cc = (ks + c) & 3;
        bf16x8 Ac[2], Bc[4];
#pragma unroll
        for (int ms = 0; ms < 2; ms++) {
            bf16x8 raw = *(const bf16x8*)(ab[ms] + (size_t)c * CSTRIDE);
            Ac[ms] = bn8(raw, scv[cc], shv[cc]);
        }
#pragma unroll
        for (int nf = 0; nf < 4; nf++) Bc[nf] = *(const bf16x8*)(bb[nf] + c * 32);
#pragma unroll
        for (int nf = 0; nf < 4; nf++)
#pragma unroll
            for (int ms = 0; ms < 2; ms++)
                acc[ms][nf] = __builtin_amdgcn_mfma_f32_16x16x32_bf16(Ac[ms], Bc[nf], acc[ms][nf], 0, 0, 0);
    }

    float* pp = part + (size_t)ks * (NIMG * 128) + (img0 + quad * 4) * 128 + nh * 64 + m;
#pragma unroll
    for (int ms = 0; ms < 2; ms++)
#pragma unroll
        for (int nf = 0; nf < 4; nf++)
#pragma unroll
            for (int r = 0; r < 4; r++)
                pp[(ms * 16 + r) * 128 + nf * 16] = acc[ms][nf][r];
}

template <int CO>
__global__ void stats_fin(const float* __restrict__ acc, const float* __restrict__ gamma,
                          const float* __restrict__ beta, float* __restrict__ st) {
    int c = threadIdx.x;
    if (c < CO) {
        const float inv = 1.0f / (8192.0f * 81.0f);
        float m = acc[c] * inv;
        float var = acc[CO + c] * inv - m * m;
        float istd = rsqrtf(var + 1e-5f);
        float sc = istd * gamma[c];
        st[c] = sc;
        st[CO + c] = beta[c] - m * sc;
    }
}

// ---- k-split reduce + bias + transpose: xT[b][f][n] = sum parts + encb ----
__global__ void enc_reduce(const float* __restrict__ part, const float* __restrict__ encb,
                           float* __restrict__ xT) {
    int i = blockIdx.x * 256 + threadIdx.x;
    const int NP = NIMG * 128;
    if (i < NP) {
        float v = part[i] + part[NP + i] + part[2 * NP + i] + part[3 * NP + i] + encb[i & 127];
        int img = i >> 7, f = i & 127;
        xT[(size_t)(img >> 7) * 16384 + f * 128 + (img & 127)] = v;
    }
}

// Y[b] = A[b] (128x128) @ S[b] (128x128)
__global__ __launch_bounds__(256) void mm_xs(const float* __restrict__ A,
        const float* __restrict__ S, float* __restrict__ Y) {
    __shared__ __align__(16) float Sc[32 * 132];
    __shared__ float Acm[32 * 33];
    int b = blockIdx.y, f0 = blockIdx.x * 32;
    int t = threadIdx.x;
    int fl = t & 31, mg = t >> 5;
    const float* Ab = A + (size_t)b * 16384;
    const float* Sb = S + (size_t)b * 16384;
    float acc[16];
#pragma unroll
    for (int j = 0; j < 16; j++) acc[j] = 0.f;
    for (int nc = 0; nc < 128; nc += 32) {
#pragma unroll
        for (int r = 0; r < 4; r++) {
            int i4 = r * 256 + t;
            int nn = i4 >> 5, m4 = (i4 & 31) * 4;
            *(float4*)&Sc[nn * 132 + m4] = *(const float4*)&Sb[(size_t)(nc + nn) * 128 + m4];
        }
#pragma unroll
        for (int r = 0; r < 4; r++) {
            int i = r * 256 + t;
            int ff = i >> 5, nn = i & 31;
            Acm[ff * 33 + nn] = Ab[(size_t)(f0 + ff) * 128 + nc + nn];
        }
        __syncthreads();
#pragma unroll 4
        for (int nn = 0; nn < 32; nn++) {
            float a = Acm[fl * 33 + nn];
#pragma unroll
            for (int j = 0; j < 4; j++) {
                float4 s4 = *(const float4*)&Sc[nn * 132 + mg * 16 + j * 4];
                acc[j*4+0] = fmaf(a, s4.x, acc[j*4+0]);
                acc[j*4+1] = fmaf(a, s4.y, acc[j*4+1]);
                acc[j*4+2] = fmaf(a, s4.z, acc[j*4+2]);
                acc[j*4+3] = fmaf(a, s4.w, acc[j*4+3]);
            }
        }
        __syncthreads();
    }
    float* yb = Y + (size_t)b * 16384 + (size_t)(f0 + fl) * 128 + mg * 16;
#pragma unroll
    for (int j = 0; j < 4; j++)
        *(float4*)&yb[j * 4] = make_float4(acc[j*4], acc[j*4+1], acc[j*4+2], acc[j*4+3]);
}

// Out[b][g][n] = relu( sum_f W0[g,f]Z0 + W1 Z1 + W2 Z2 + bias[g] )
__global__ __launch_bounds__(256) void gf_combine(const float* __restrict__ Z0,
        const float* __restrict__ Z1, const float* __restrict__ Z2,
        const float* __restrict__ W, const float* __restrict__ bias,
        float* __restrict__ out) {
    __shared__ __align__(16) float Zc[32 * 132];
    __shared__ float Wc[32 * 33];
    int b = blockIdx.y, g0 = blockIdx.x * 32;
    int t = threadIdx.x;
    int gl = t & 31, mg = t >> 5;
    float acc[16];
    float bb = bias[g0 + gl];
#pragma unroll
    for (int j = 0; j < 16; j++) acc[j] = bb;
    const float* Zs[3] = {Z0 + (size_t)b * 16384, Z1 + (size_t)b * 16384, Z2 + (size_t)b * 16384};
    for (int j3 = 0; j3 < 3; j3++) {
        const float* Zb = Zs[j3];
        const float* Wj = W + j3 * 16384;
        for (int fc = 0; fc < 128; fc += 32) {
#pragma unroll
            for (int r = 0; r < 4; r++) {
                int i4 = r * 256 + t;
                int ff = i4 >> 5, m4 = (i4 & 31) * 4;
                *(float4*)&Zc[ff * 132 + m4] = *(const float4*)&Zb[(size_t)(fc + ff) * 128 + m4];
            }
#pragma unroll
            for (int r = 0; r < 4; r++) {
                int i = r * 256 + t;
                int gg = i >> 5, ff = i & 31;
                Wc[gg * 33 + ff] = Wj[(size_t)(g0 + gg) * 128 + fc + ff];
            }
            __syncthreads();
#pragma unroll 4
            for (int ff = 0; ff < 32; ff++) {
                float w = Wc[gl * 33 + ff];
#pragma unroll
                for (int j = 0; j < 4; j++) {
                    float4 z4 = *(const float4*)&Zc[ff * 132 + mg * 16 + j * 4];
                    acc[j*4+0] = fmaf(w, z4.x, acc[j*4+0]);
                    acc[j*4+1] = fmaf(w, z4.y, acc[j*4+1]);
                    acc[j*4+2] = fmaf(w, z4.z, acc[j*4+2]);
                    acc[j*4+3] = fmaf(w, z4.w, acc[j*4+3]);
                }
            }
            __syncthreads();
        }
    }
    float* ob = out + (size_t)b * 16384 + (size_t)(g0 + gl) * 128 + mg * 16;
#pragma unroll
    for (int j = 0; j < 4; j++)
        *(float4*)&ob[j * 4] = make_float4(fmaxf(acc[j*4], 0.f), fmaxf(acc[j*4+1], 0.f),
                                           fmaxf(acc[j*4+2], 0.f), fmaxf(acc[j*4+3], 0.f));
}

// logits[b,n,a] = sum_g X[b][g][n] * aw[a][g] + ab[a]
__global__ __launch_bounds__(128) void act_kernel(const float* __restrict__ X,
        const float* __restrict__ aw, const float* __restrict__ ab,
        float* __restrict__ out) {
    int b = blockIdx.x, n = threadIdx.x;
    float acc[5];
#pragma unroll
    for (int a = 0; a < 5; a++) acc[a] = ab[a];
    const float* xb = X + (size_t)b * 16384 + n;
#pragma unroll 4
    for (int g = 0; g < 128; g++) {
        float v = xb[(size_t)g * 128];
#pragma unroll
        for (int a = 0; a < 5; a++) acc[a] = fmaf(v, aw[a * 128 + g], acc[a]);
    }
    float* ob = out + ((size_t)b * 128 + n) * 5;
#pragma unroll
    for (int a = 0; a < 5; a++) ob[a] = acc[a];
}

// ---------------------------------------------------------------------------
extern "C" void kernel_launch(void* const* d_in, const int* in_sizes, int n_in,
                              void* d_out, int out_size, void* d_ws, size_t ws_size,
                              hipStream_t stream) {
    const float* states = (const float*)d_in[0];
    const float* gso    = (const float*)d_in[1];
    const float* c1w  = (const float*)d_in[2];
    const float* c1b  = (const float*)d_in[3];
    const float* c1g  = (const float*)d_in[4];
    const float* c1be = (const float*)d_in[5];
    const float* c2w  = (const float*)d_in[6];
    const float* c2b  = (const float*)d_in[7];
    const float* c2g  = (const float*)d_in[8];
    const float* c2be = (const float*)d_in[9];
    const float* c3w  = (const float*)d_in[10];
    const float* c3b  = (const float*)d_in[11];
    const float* c3g  = (const float*)d_in[12];
    const float* c3be = (const float*)d_in[13];
    const float* encw = (const float*)d_in[14];
    const float* encb = (const float*)d_in[15];
    const float* g1w  = (const float*)d_in[16];
    const float* g1b  = (const float*)d_in[17];
    const float* g2w  = (const float*)d_in[18];
    const float* g2b  = (const float*)d_in[19];
    const float* aw   = (const float*)d_in[20];
    const float* ab   = (const float*)d_in[21];
    float* out = (float*)d_out;
    char* ws = (char*)d_ws;

    size_t o = 0;
    auto take = [&](size_t bytes) { size_t r = o; o += (bytes + 255) & ~(size_t)255; return r; };
    const size_t o_x3  = take((size_t)81 * 4 * NIMG * 32 * 2);   // 169,869,312
    const size_t o_x2  = take((size_t)81 * 2 * NIMG * 32 * 2);   //  84,934,656
    const size_t o_w1t = take(27 * 32 * 4);
    const size_t o_w2m = take(64 * 288 * 2);
    const size_t o_w3m = take(128 * 576 * 2);
    const size_t o_acc = take(448 * 4);
    const size_t o_st1 = take(2 * 32 * 4);
    const size_t o_st2 = take(2 * 64 * 4);
    const size_t o_st3 = take(2 * 128 * 4);
    if (ws_size < o) {
        fill_sentinel<<<(out_size + 255) / 256, 256, 0, stream>>>(out, out_size);
        return;
    }

    const size_t o_x1 = o_x3;                       // x1 (42.5MB) at head of x3 region
    const size_t o_ewb  = o_x2;                     // 2,654,208 (aliases dead x2)
    const size_t o_part = o_x2 + 2654208;           // 16,777,216 (4 k-split partials)
    const size_t o_xT   = o_part + 16777216;
    const size_t o_y1   = o_xT + 4194304;
    const size_t o_y2   = o_y1 + 4194304;
    const size_t o_G1   = o_y2 + 4194304;
    const size_t o_G2   = o_G1 + 4194304;           // ends ~40MB < 85MB region

    bf16* x1 = (bf16*)(ws + o_x1);
    bf16* x2 = (bf16*)(ws + o_x2);
    bf16* x3 = (bf16*)(ws + o_x3);
    float* w1t = (float*)(ws + o_w1t);
    bf16* w2m = (bf16*)(ws + o_w2m);
    bf16* w3m = (bf16*)(ws + o_w3m);
    float* acc1 = (float*)(ws + o_acc);
    float* acc2 = acc1 + 64;
    float* acc3 = acc1 + 192;
    float* st1 = (float*)(ws + o_st1);
    float* st2 = (float*)(ws + o_st2);
    float* st3 = (float*)(ws + o_st3);
    bf16* ewb = (bf16*)(ws + o_ewb);
    float* partp = (float*)(ws + o_part);
    float* xT = (float*)(ws + o_xT);
    float* y1 = (float*)(ws + o_y1);
    float* y2 = (float*)(ws + o_y2);
    float* xG1 = (float*)(ws + o_G1);
    float* xG2 = (float*)(ws + o_G2);

    hipMemsetAsync(ws + o_acc, 0, 448 * 4, stream);
    prep_w<<<128, 256, 0, stream>>>(c1w, c2w, c3w, w1t, w2m, w3m);

    conv1_kernel<<<2048, 128, 0, stream>>>(states, w1t, c1b, x1, acc1);
    stats_fin<32><<<1, 32, 0, stream>>>(acc1, c1g, c1be, st1);

    conv_tile<32, 64, 1><<<2592, 256, 0, stream>>>(x1, w2m, c2b, st1, x2, acc2);
    stats_fin<64><<<1, 64, 0, stream>>>(acc2, c2g, c2be, st2);

    conv_tile<64, 128, 2><<<5184, 256, 0, stream>>>(x2, w3m, c3b, st2, x3, acc3);
    stats_fin<128><<<1, 128, 0, stream>>>(acc3, c3g, c3be, st3);

    prep_enc<<<2048, 256, 0, stream>>>(encw, ewb);
    enc_mfma<<<512, 256, 0, stream>>>(x3, ewb, st3, partp);
    enc_reduce<<<4096, 256, 0, stream>>>(partp, encb, xT);

    mm_xs<<<dim3(4, 64), 256, 0, stream>>>(xT, gso, y1);
    mm_xs<<<dim3(4, 64), 256, 0, stream>>>(y1, gso, y2);
    gf_combine<<<dim3(4, 64), 256, 0, stream>>>(xT, y1, y2, g1w, g1b, xG1);

    mm_xs<<<dim3(4, 64), 256, 0, stream>>>(xG1, gso, y1);
    mm_xs<<<dim3(4, 64), 256, 0, stream>>>(y1, gso, y2);
    gf_combine<<<dim3(4, 64), 256, 0, stream>>>(xG1, y1, y2, g2w, g2b, xG2);

    act_kernel<<<64, 128, 0, stream>>>(xG2, aw, ab, out);
}